// Round 1
// baseline (7561.157 us; speedup 1.0000x reference)
//
#include <hip/hip_runtime.h>
#include <hip/hip_bf16.h>

// ---------------------------------------------------------------------------
// Pq/Pk/Pv = W_word @ {Wq,Wk,Wv}   (one wave per row; lane = output column)
// ---------------------------------------------------------------------------
__global__ void proj_kernel(const float* __restrict__ W_word,
                            const float* __restrict__ Wq,
                            const float* __restrict__ Wk,
                            const float* __restrict__ Wv,
                            float* __restrict__ Pq, float* __restrict__ Pk,
                            float* __restrict__ Pv, int nrows) {
    int wid  = (blockIdx.x * blockDim.x + threadIdx.x) >> 6;
    int lane = threadIdx.x & 63;
    if (wid >= nrows) return;
    float x = W_word[(size_t)wid * 64 + lane];
    float aq = 0.f, ak = 0.f, av = 0.f;
#pragma unroll
    for (int i = 0; i < 64; i++) {
        float xi = __shfl(x, i, 64);  // readlane broadcast
        aq = fmaf(xi, Wq[i * 64 + lane], aq);
        ak = fmaf(xi, Wk[i * 64 + lane], ak);
        av = fmaf(xi, Wv[i * 64 + lane], av);
    }
    size_t o = (size_t)wid * 64 + lane;
    Pq[o] = aq; Pk[o] = ak; Pv[o] = av;
}

// ---------------------------------------------------------------------------
// copy [rows,64] source into first half of [rows,128] dest (float4 lanes)
// ---------------------------------------------------------------------------
__global__ void copy_half_kernel(const float4* __restrict__ src,
                                 float4* __restrict__ dst, int rows) {
    int t = blockIdx.x * blockDim.x + threadIdx.x;
    int n16 = rows * 16;
    if (t >= n16) return;
    int r = t >> 4, c = t & 15;
    dst[(size_t)r * 32 + c] = src[t];
}

// ---------------------------------------------------------------------------
// MHSA + mean over L=8, fused @Wo. One wave per sequence; lane = column
// j = h*16+d  (H=4, hd=16).
// mode 0: out[wid*128+64+lane] = h            (h_query into q_e0 high half)
// mode 1: atomicAdd into out[dst*128+64+lane]; lane0 counts deg  (reviews)
// mode 2: out[wid*64+lane] = h                (batch qb)
// ---------------------------------------------------------------------------
__global__ void mhsa_kernel(const float* __restrict__ Pq,
                            const float* __restrict__ Pk,
                            const float* __restrict__ Pv,
                            const float* __restrict__ Wo,
                            const int* __restrict__ ids, int nseq, int mode,
                            float* __restrict__ out,
                            const int* __restrict__ dst_idx,
                            float* __restrict__ deg) {
    int wid  = (blockIdx.x * blockDim.x + threadIdx.x) >> 6;
    int lane = threadIdx.x & 63;
    if (wid >= nseq) return;
    const int* idr = ids + (size_t)wid * 8;
    float qr[8], kr[8], vr[8];
#pragma unroll
    for (int l = 0; l < 8; l++) {
        int id = idr[l];
        size_t o = (size_t)id * 64 + lane;
        qr[l] = Pq[o]; kr[l] = Pk[o]; vr[l] = Pv[o];
    }
    float wacc[8] = {0.f, 0.f, 0.f, 0.f, 0.f, 0.f, 0.f, 0.f};
#pragma unroll
    for (int l = 0; l < 8; l++) {
        float sc[8];
#pragma unroll
        for (int m = 0; m < 8; m++) {
            float p = qr[l] * kr[m];
            p += __shfl_xor(p, 8, 16);   // reduce d within 16-lane head group
            p += __shfl_xor(p, 4, 16);
            p += __shfl_xor(p, 2, 16);
            p += __shfl_xor(p, 1, 16);
            sc[m] = p * 0.25f;           // / sqrt(hd=16)
        }
        float mx = sc[0];
#pragma unroll
        for (int m = 1; m < 8; m++) mx = fmaxf(mx, sc[m]);
        float ex[8]; float sum = 0.f;
#pragma unroll
        for (int m = 0; m < 8; m++) { ex[m] = __expf(sc[m] - mx); sum += ex[m]; }
        float f = 0.125f / sum;          // mean over L folded in
#pragma unroll
        for (int m = 0; m < 8; m++) wacc[m] = fmaf(ex[m], f, wacc[m]);
    }
    float om = 0.f;
#pragma unroll
    for (int m = 0; m < 8; m++) om = fmaf(wacc[m], vr[m], om);
    // fused @ Wo: h[lane] = sum_i om[i] * Wo[i][lane]
    float h = 0.f;
#pragma unroll
    for (int i = 0; i < 64; i++) {
        float oi = __shfl(om, i, 64);
        h = fmaf(oi, Wo[i * 64 + lane], h);
    }
    if (mode == 0) {
        out[(size_t)wid * 128 + 64 + lane] = h;
    } else if (mode == 1) {
        int d = dst_idx[wid];
        unsafeAtomicAdd(&out[(size_t)d * 128 + 64 + lane], h);
        if (lane == 0) unsafeAtomicAdd(&deg[d], 1.0f);
    } else {
        out[(size_t)wid * 64 + lane] = h;
    }
}

// normalize ent_h half of e0 by max(deg_p,1)
__global__ void norm_kernel(float* __restrict__ e0,
                            const float* __restrict__ degp, int N) {
    int t = blockIdx.x * blockDim.x + threadIdx.x;
    if (t >= N * 16) return;
    int r = t >> 4, c = t & 15;
    float s = 1.0f / fmaxf(degp[r], 1.0f);
    float4* p = (float4*)(e0 + (size_t)r * 128 + 64) + c;
    float4 v = *p;
    v.x *= s; v.y *= s; v.z *= s; v.w *= s;
    *p = v;
}

// deg_i accumulation from both endpoints
__global__ void deg_kernel(const int* __restrict__ p_src,
                           const int* __restrict__ p_dst,
                           float* __restrict__ degi, int E) {
    int t = blockIdx.x * blockDim.x + threadIdx.x;
    if (t >= E) return;
    unsafeAtomicAdd(&degi[p_src[t]], 1.0f);
    unsafeAtomicAdd(&degi[p_dst[t]], 1.0f);
}

__global__ void inv_kernel(float* __restrict__ degi, int N) {
    int t = blockIdx.x * blockDim.x + threadIdx.x;
    if (t >= N) return;
    degi[t] = 1.0f / sqrtf(fmaxf(degi[t], 1.0f));
}

// ---------------------------------------------------------------------------
// graph conv: 32 threads per edge, float4 per thread (128 cols)
// agg[dst] += e0[src] + q_e0[qid]*inv[src];  agg[src] += e0[dst]*inv[dst]
// ---------------------------------------------------------------------------
__global__ void conv_kernel(const float* __restrict__ e0,
                            const float* __restrict__ qe0,
                            const float* __restrict__ inv,
                            const int* __restrict__ p_src,
                            const int* __restrict__ p_dst,
                            const int* __restrict__ p_qid,
                            float* __restrict__ agg, int E) {
    int t = blockIdx.x * blockDim.x + threadIdx.x;
    int e = t >> 5, c = (t & 31) * 4;
    if (e >= E) return;
    int src = p_src[e], dst = p_dst[e], qid = p_qid[e];
    float is = inv[src], id_ = inv[dst];
    const float4 es = *(const float4*)(e0  + (size_t)src * 128 + c);
    const float4 qe = *(const float4*)(qe0 + (size_t)qid * 128 + c);
    const float4 ed = *(const float4*)(e0  + (size_t)dst * 128 + c);
    float* ad = agg + (size_t)dst * 128 + c;
    float* as = agg + (size_t)src * 128 + c;
    unsafeAtomicAdd(ad + 0, fmaf(qe.x, is, es.x));
    unsafeAtomicAdd(ad + 1, fmaf(qe.y, is, es.y));
    unsafeAtomicAdd(ad + 2, fmaf(qe.z, is, es.z));
    unsafeAtomicAdd(ad + 3, fmaf(qe.w, is, es.w));
    unsafeAtomicAdd(as + 0, ed.x * id_);
    unsafeAtomicAdd(as + 1, ed.y * id_);
    unsafeAtomicAdd(as + 2, ed.z * id_);
    unsafeAtomicAdd(as + 3, ed.w * id_);
}

// ---------------------------------------------------------------------------
// final gather: e(n,c) = 0.5*(e0 + agg*inv);  3 output blocks
// ---------------------------------------------------------------------------
__global__ void out_kernel(const float* __restrict__ e0,
                           const float* __restrict__ agg,
                           const float* __restrict__ inv,
                           const float* __restrict__ qb,
                           const int* __restrict__ users,
                           const int* __restrict__ items,
                           const int* __restrict__ negs,
                           float* __restrict__ out, int B) {
    int t = blockIdx.x * blockDim.x + threadIdx.x;
    if (t >= B * 128) return;
    int b = t >> 7, c = t & 127;
    int u = users[b], it = items[b], ng = negs[b];
    size_t ou = (size_t)u * 128 + c, oi = (size_t)it * 128 + c, on = (size_t)ng * 128 + c;
    float eu = 0.5f * fmaf(agg[ou], inv[u], e0[ou]);
    float ei = 0.5f * fmaf(agg[oi], inv[it], e0[oi]);
    float en = 0.5f * fmaf(agg[on], inv[ng], e0[on]);
    float q = (c >= 64) ? qb[(size_t)b * 64 + (c - 64)] : 0.0f;
    out[t] = eu + q;
    out[(size_t)B * 128 + t] = ei;
    out[(size_t)B * 256 + t] = en;
}

// ---------------------------------------------------------------------------
extern "C" void kernel_launch(void* const* d_in, const int* in_sizes, int n_in,
                              void* d_out, int out_size, void* d_ws, size_t ws_size,
                              hipStream_t stream) {
    const float* W_word   = (const float*)d_in[0];
    const float* W_query  = (const float*)d_in[1];
    const float* W_entity = (const float*)d_in[2];
    const float* Wq       = (const float*)d_in[3];
    const float* Wk       = (const float*)d_in[4];
    const float* Wv       = (const float*)d_in[5];
    const float* Wo       = (const float*)d_in[6];
    const int* query_word_ids  = (const int*)d_in[7];
    const int* review_word_ids = (const int*)d_in[8];
    const int* profile_dst     = (const int*)d_in[9];
    const int* p_src  = (const int*)d_in[10];
    const int* p_dst  = (const int*)d_in[11];
    const int* p_qid  = (const int*)d_in[12];
    const int* users  = (const int*)d_in[13];
    const int* items  = (const int*)d_in[14];
    const int* negs   = (const int*)d_in[15];
    const int* query_words = (const int*)d_in[16];

    const int WORD = in_sizes[0] / 64;   // 50000
    const int Qn   = in_sizes[1] / 64;   // 50000
    const int N    = in_sizes[2] / 64;   // 100000
    const int R    = in_sizes[8] / 8;    // 100000
    const int E    = in_sizes[10];       // 2000000
    const int B    = in_sizes[13];       // 1024

    float* ws   = (float*)d_ws;
    float* e0   = ws;                          // [N,128]
    float* agg  = e0   + (size_t)N * 128;      // [N,128]
    float* degp = agg  + (size_t)N * 128;      // [N]
    float* degi = degp + N;                    // [N]
    float* Pq   = degi + N;                    // [WORD,64]
    float* Pk   = Pq   + (size_t)WORD * 64;
    float* Pv   = Pk   + (size_t)WORD * 64;
    float* qe0  = Pv   + (size_t)WORD * 64;    // [Qn,128]
    float* qb   = qe0  + (size_t)Qn * 128;     // [B,64]

    // zero accumulators (e0, agg, degp, degi) — contiguous
    hipMemsetAsync(e0, 0, ((size_t)N * 256 + 2 * (size_t)N) * sizeof(float), stream);

    // projections
    proj_kernel<<<(WORD + 3) / 4, 256, 0, stream>>>(W_word, Wq, Wk, Wv, Pq, Pk, Pv, WORD);

    // first halves of q_e0 / e0
    copy_half_kernel<<<(Qn * 16 + 255) / 256, 256, 0, stream>>>((const float4*)W_query, (float4*)qe0, Qn);
    copy_half_kernel<<<(N * 16 + 255) / 256, 256, 0, stream>>>((const float4*)W_entity, (float4*)e0, N);

    // MHSA: queries -> q_e0 high half; reviews -> scatter into e0 high half; batch -> qb
    mhsa_kernel<<<(Qn + 3) / 4, 256, 0, stream>>>(Pq, Pk, Pv, Wo, query_word_ids, Qn, 0, qe0, nullptr, nullptr);
    mhsa_kernel<<<(R + 3) / 4, 256, 0, stream>>>(Pq, Pk, Pv, Wo, review_word_ids, R, 1, e0, profile_dst, degp);
    mhsa_kernel<<<(B + 3) / 4, 256, 0, stream>>>(Pq, Pk, Pv, Wo, query_words, B, 2, qb, nullptr, nullptr);

    // ent_h /= max(deg_p,1)
    norm_kernel<<<(N * 16 + 255) / 256, 256, 0, stream>>>(e0, degp, N);

    // interaction degrees -> inv_sqrt (in place in degi)
    deg_kernel<<<(E + 255) / 256, 256, 0, stream>>>(p_src, p_dst, degi, E);
    inv_kernel<<<(N + 255) / 256, 256, 0, stream>>>(degi, N);

    // graph conv (atomic scatter)
    {
        long long total = (long long)E * 32;
        int blocks = (int)((total + 255) / 256);
        conv_kernel<<<blocks, 256, 0, stream>>>(e0, qe0, degi, p_src, p_dst, p_qid, agg, E);
    }

    // gather outputs
    out_kernel<<<(B * 128 + 255) / 256, 256, 0, stream>>>(e0, agg, degi, qb, users, items, negs, (float*)d_out, B);
}

// Round 2
// 1575.590 us; speedup vs baseline: 4.7989x; 4.7989x over previous
//
#include <hip/hip_runtime.h>
#include <hip/hip_bf16.h>

// ---------------------------------------------------------------------------
// Pq/Pk/Pv = W_word @ {Wq,Wk,Wv}   (one wave per row; lane = output column)
// ---------------------------------------------------------------------------
__global__ void proj_kernel(const float* __restrict__ W_word,
                            const float* __restrict__ Wq,
                            const float* __restrict__ Wk,
                            const float* __restrict__ Wv,
                            float* __restrict__ Pq, float* __restrict__ Pk,
                            float* __restrict__ Pv, int nrows) {
    int wid  = (blockIdx.x * blockDim.x + threadIdx.x) >> 6;
    int lane = threadIdx.x & 63;
    if (wid >= nrows) return;
    float x = W_word[(size_t)wid * 64 + lane];
    float aq = 0.f, ak = 0.f, av = 0.f;
#pragma unroll
    for (int i = 0; i < 64; i++) {
        float xi = __shfl(x, i, 64);
        aq = fmaf(xi, Wq[i * 64 + lane], aq);
        ak = fmaf(xi, Wk[i * 64 + lane], ak);
        av = fmaf(xi, Wv[i * 64 + lane], av);
    }
    size_t o = (size_t)wid * 64 + lane;
    Pq[o] = aq; Pk[o] = ak; Pv[o] = av;
}

// ---------------------------------------------------------------------------
// copy [rows,64] source into first half of [rows,128] dest (float4 lanes)
// ---------------------------------------------------------------------------
__global__ void copy_half_kernel(const float4* __restrict__ src,
                                 float4* __restrict__ dst, int rows) {
    int t = blockIdx.x * blockDim.x + threadIdx.x;
    int n16 = rows * 16;
    if (t >= n16) return;
    int r = t >> 4, c = t & 15;
    dst[(size_t)r * 32 + c] = src[t];
}

// ---------------------------------------------------------------------------
// MHSA + mean over L=8, fused @Wo. One wave per sequence; lane = col.
// mode 0: out[wid*128+64+lane] = h   mode 1: atomic scatter into e0 + deg
// mode 2: out[wid*64+lane] = h
// ---------------------------------------------------------------------------
__global__ void mhsa_kernel(const float* __restrict__ Pq,
                            const float* __restrict__ Pk,
                            const float* __restrict__ Pv,
                            const float* __restrict__ Wo,
                            const int* __restrict__ ids, int nseq, int mode,
                            float* __restrict__ out,
                            const int* __restrict__ dst_idx,
                            float* __restrict__ deg) {
    int wid  = (blockIdx.x * blockDim.x + threadIdx.x) >> 6;
    int lane = threadIdx.x & 63;
    if (wid >= nseq) return;
    const int* idr = ids + (size_t)wid * 8;
    float qr[8], kr[8], vr[8];
#pragma unroll
    for (int l = 0; l < 8; l++) {
        int id = idr[l];
        size_t o = (size_t)id * 64 + lane;
        qr[l] = Pq[o]; kr[l] = Pk[o]; vr[l] = Pv[o];
    }
    float wacc[8] = {0.f, 0.f, 0.f, 0.f, 0.f, 0.f, 0.f, 0.f};
#pragma unroll
    for (int l = 0; l < 8; l++) {
        float sc[8];
#pragma unroll
        for (int m = 0; m < 8; m++) {
            float p = qr[l] * kr[m];
            p += __shfl_xor(p, 8, 16);
            p += __shfl_xor(p, 4, 16);
            p += __shfl_xor(p, 2, 16);
            p += __shfl_xor(p, 1, 16);
            sc[m] = p * 0.25f;
        }
        float mx = sc[0];
#pragma unroll
        for (int m = 1; m < 8; m++) mx = fmaxf(mx, sc[m]);
        float ex[8]; float sum = 0.f;
#pragma unroll
        for (int m = 0; m < 8; m++) { ex[m] = __expf(sc[m] - mx); sum += ex[m]; }
        float f = 0.125f / sum;
#pragma unroll
        for (int m = 0; m < 8; m++) wacc[m] = fmaf(ex[m], f, wacc[m]);
    }
    float om = 0.f;
#pragma unroll
    for (int m = 0; m < 8; m++) om = fmaf(wacc[m], vr[m], om);
    float h = 0.f;
#pragma unroll
    for (int i = 0; i < 64; i++) {
        float oi = __shfl(om, i, 64);
        h = fmaf(oi, Wo[i * 64 + lane], h);
    }
    if (mode == 0) {
        out[(size_t)wid * 128 + 64 + lane] = h;
    } else if (mode == 1) {
        int d = dst_idx[wid];
        unsafeAtomicAdd(&out[(size_t)d * 128 + 64 + lane], h);
        if (lane == 0) unsafeAtomicAdd(&deg[d], 1.0f);
    } else {
        out[(size_t)wid * 64 + lane] = h;
    }
}

// normalize ent_h half of e0 by max(deg_p,1)
__global__ void norm_kernel(float* __restrict__ e0,
                            const float* __restrict__ degp, int N) {
    int t = blockIdx.x * blockDim.x + threadIdx.x;
    if (t >= N * 16) return;
    int r = t >> 4, c = t & 15;
    float s = 1.0f / fmaxf(degp[r], 1.0f);
    float4* p = (float4*)(e0 + (size_t)r * 128 + 64) + c;
    float4 v = *p;
    v.x *= s; v.y *= s; v.z *= s; v.w *= s;
    *p = v;
}

// int degree accumulation from both endpoints
__global__ void deg_kernel(const int* __restrict__ p_src,
                           const int* __restrict__ p_dst,
                           int* __restrict__ degc, int E) {
    int t = blockIdx.x * blockDim.x + threadIdx.x;
    if (t >= E) return;
    atomicAdd(&degc[p_src[t]], 1);
    atomicAdd(&degc[p_dst[t]], 1);
}

__global__ void inv_kernel(const int* __restrict__ degc,
                           float* __restrict__ inv, int N) {
    int t = blockIdx.x * blockDim.x + threadIdx.x;
    if (t >= N) return;
    inv[t] = 1.0f / sqrtf((float)max(degc[t], 1));
}

// ---------------------------------------------------------------------------
// prefix scan of degc (N elems) in 1024-chunks: offs (exclusive), cursor copy
// ---------------------------------------------------------------------------
__global__ void scan_sum(const int* __restrict__ degc, int* __restrict__ csum,
                         int N) {
    __shared__ int red[4];
    int chunk = blockIdx.x, t = threadIdx.x;
    int base = chunk * 1024;
    int v = 0;
#pragma unroll
    for (int k = 0; k < 4; k++) {
        int idx = base + t * 4 + k;
        if (idx < N) v += degc[idx];
    }
#pragma unroll
    for (int o = 32; o; o >>= 1) v += __shfl_down(v, o, 64);
    if ((t & 63) == 0) red[t >> 6] = v;
    __syncthreads();
    if (t == 0) csum[chunk] = red[0] + red[1] + red[2] + red[3];
}

__global__ void scan_blocks(int* __restrict__ csum, int nchunk) {
    if (threadIdx.x == 0 && blockIdx.x == 0) {
        int a = 0;
        for (int i = 0; i < nchunk; i++) { int v = csum[i]; csum[i] = a; a += v; }
    }
}

__global__ void scan_chunk(const int* __restrict__ degc,
                           const int* __restrict__ csum,
                           int* __restrict__ offs, int* __restrict__ cursor,
                           int N) {
    __shared__ int lds[256];
    int chunk = blockIdx.x, t = threadIdx.x;
    int base = chunk * 1024 + t * 4;
    int v0 = (base + 0 < N) ? degc[base + 0] : 0;
    int v1 = (base + 1 < N) ? degc[base + 1] : 0;
    int v2 = (base + 2 < N) ? degc[base + 2] : 0;
    int v3 = (base + 3 < N) ? degc[base + 3] : 0;
    int s = v0 + v1 + v2 + v3;
    lds[t] = s;
    __syncthreads();
    for (int o = 1; o < 256; o <<= 1) {
        int u = (t >= o) ? lds[t - o] : 0;
        __syncthreads();
        lds[t] += u;
        __syncthreads();
    }
    int tb = lds[t] - s + csum[chunk];  // exclusive base for this thread
    int vv[4] = {v0, v1, v2, v3};
#pragma unroll
    for (int k = 0; k < 4; k++) {
        int idx = base + k;
        if (idx < N) {
            offs[idx] = tb; cursor[idx] = tb; tb += vv[k];
            if (idx == N - 1) offs[N] = tb;
        }
    }
}

// ---------------------------------------------------------------------------
// scatter edge messages into per-node buckets (8B payload, int cursor atomics)
// msg.x = other node, msg.y = qid (>=0: forward msg) or -1 (reverse msg)
// ---------------------------------------------------------------------------
__global__ void scatter_msgs(const int* __restrict__ p_src,
                             const int* __restrict__ p_dst,
                             const int* __restrict__ p_qid,
                             int* __restrict__ cursor, int2* __restrict__ msg,
                             int E) {
    int e = blockIdx.x * blockDim.x + threadIdx.x;
    if (e >= E) return;
    int s = p_src[e], d = p_dst[e], q = p_qid[e];
    int slot1 = atomicAdd(&cursor[d], 1);
    msg[slot1] = make_int2(s, q);
    int slot2 = atomicAdd(&cursor[s], 1);
    msg[slot2] = make_int2(d, -1);
}

// ---------------------------------------------------------------------------
// CSR gather: 32 threads per node, float4 per thread; one clean write per node
// ---------------------------------------------------------------------------
__global__ void gather_conv(const float* __restrict__ e0,
                            const float* __restrict__ qe0,
                            const float* __restrict__ inv,
                            const int* __restrict__ offs,
                            const int2* __restrict__ msg,
                            float* __restrict__ agg, int N) {
    int g = (blockIdx.x * blockDim.x + threadIdx.x) >> 5;
    int c = (threadIdx.x & 31) * 4;
    if (g >= N) return;
    int beg = offs[g], end = offs[g + 1];
    float ax = 0.f, ay = 0.f, az = 0.f, aw = 0.f;
    for (int m = beg; m < end; m++) {
        int2 mm = msg[m];
        float w = inv[mm.x];
        const float4 ev = *(const float4*)(e0 + (size_t)mm.x * 128 + c);
        if (mm.y >= 0) {
            const float4 qv = *(const float4*)(qe0 + (size_t)mm.y * 128 + c);
            ax += fmaf(qv.x, w, ev.x); ay += fmaf(qv.y, w, ev.y);
            az += fmaf(qv.z, w, ev.z); aw += fmaf(qv.w, w, ev.w);
        } else {
            ax = fmaf(ev.x, w, ax); ay = fmaf(ev.y, w, ay);
            az = fmaf(ev.z, w, az); aw = fmaf(ev.w, w, aw);
        }
    }
    float4 r; r.x = ax; r.y = ay; r.z = az; r.w = aw;
    *(float4*)(agg + (size_t)g * 128 + c) = r;
}

// ---------------------------------------------------------------------------
// final gather: e(n,c) = 0.5*(e0 + agg*inv);  3 output blocks
// ---------------------------------------------------------------------------
__global__ void out_kernel(const float* __restrict__ e0,
                           const float* __restrict__ agg,
                           const float* __restrict__ inv,
                           const float* __restrict__ qb,
                           const int* __restrict__ users,
                           const int* __restrict__ items,
                           const int* __restrict__ negs,
                           float* __restrict__ out, int B) {
    int t = blockIdx.x * blockDim.x + threadIdx.x;
    if (t >= B * 128) return;
    int b = t >> 7, c = t & 127;
    int u = users[b], it = items[b], ng = negs[b];
    size_t ou = (size_t)u * 128 + c, oi = (size_t)it * 128 + c, on = (size_t)ng * 128 + c;
    float eu = 0.5f * fmaf(agg[ou], inv[u], e0[ou]);
    float ei = 0.5f * fmaf(agg[oi], inv[it], e0[oi]);
    float en = 0.5f * fmaf(agg[on], inv[ng], e0[on]);
    float q = (c >= 64) ? qb[(size_t)b * 64 + (c - 64)] : 0.0f;
    out[t] = eu + q;
    out[(size_t)B * 128 + t] = ei;
    out[(size_t)B * 256 + t] = en;
}

// ---------------------------------------------------------------------------
extern "C" void kernel_launch(void* const* d_in, const int* in_sizes, int n_in,
                              void* d_out, int out_size, void* d_ws, size_t ws_size,
                              hipStream_t stream) {
    const float* W_word   = (const float*)d_in[0];
    const float* W_query  = (const float*)d_in[1];
    const float* W_entity = (const float*)d_in[2];
    const float* Wq       = (const float*)d_in[3];
    const float* Wk       = (const float*)d_in[4];
    const float* Wv       = (const float*)d_in[5];
    const float* Wo       = (const float*)d_in[6];
    const int* query_word_ids  = (const int*)d_in[7];
    const int* review_word_ids = (const int*)d_in[8];
    const int* profile_dst     = (const int*)d_in[9];
    const int* p_src  = (const int*)d_in[10];
    const int* p_dst  = (const int*)d_in[11];
    const int* p_qid  = (const int*)d_in[12];
    const int* users  = (const int*)d_in[13];
    const int* items  = (const int*)d_in[14];
    const int* negs   = (const int*)d_in[15];
    const int* query_words = (const int*)d_in[16];

    const int WORD = in_sizes[0] / 64;   // 50000
    const int Qn   = in_sizes[1] / 64;   // 50000
    const int N    = in_sizes[2] / 64;   // 100000
    const int R    = in_sizes[8] / 8;    // 100000
    const int E    = in_sizes[10];       // 2000000
    const int B    = in_sizes[13];       // 1024

    float* ws   = (float*)d_ws;
    float* e0   = ws;                          // [N,128]
    float* degp = e0   + (size_t)N * 128;      // [N]
    int*   degc = (int*)(degp + N);            // [N] (int)
    float* agg  = (float*)(degc + N);          // [N,128]
    float* Pq   = agg  + (size_t)N * 128;      // [WORD,64]
    float* Pk   = Pq   + (size_t)WORD * 64;
    float* Pv   = Pk   + (size_t)WORD * 64;
    float* qe0  = Pv   + (size_t)WORD * 64;    // [Qn,128]
    float* qb   = qe0  + (size_t)Qn * 128;     // [B,64]
    float* inv  = qb   + (size_t)B * 64;       // [N]
    int*  offs  = (int*)(inv + N);             // [N+1]
    int* cursor = offs + (N + 1);              // [N]
    int*  csum  = cursor + N;                  // [nchunk]
    // message buffer overlays Pq/Pk/Pv (dead after the 3 mhsa launches):
    // need 2E * 8B = 32 MB <= WORD*64*3*4B = 38.4 MB
    int2* msg   = (int2*)Pq;

    const int nchunk = (N + 1023) / 1024;

    // zero e0, degp, degc (contiguous)
    hipMemsetAsync(e0, 0, ((size_t)N * 128 + 2 * (size_t)N) * sizeof(float), stream);

    // projections
    proj_kernel<<<(WORD + 3) / 4, 256, 0, stream>>>(W_word, Wq, Wk, Wv, Pq, Pk, Pv, WORD);

    // first halves of q_e0 / e0
    copy_half_kernel<<<(Qn * 16 + 255) / 256, 256, 0, stream>>>((const float4*)W_query, (float4*)qe0, Qn);
    copy_half_kernel<<<(N * 16 + 255) / 256, 256, 0, stream>>>((const float4*)W_entity, (float4*)e0, N);

    // MHSA passes
    mhsa_kernel<<<(Qn + 3) / 4, 256, 0, stream>>>(Pq, Pk, Pv, Wo, query_word_ids, Qn, 0, qe0, nullptr, nullptr);
    mhsa_kernel<<<(R + 3) / 4, 256, 0, stream>>>(Pq, Pk, Pv, Wo, review_word_ids, R, 1, e0, profile_dst, degp);
    mhsa_kernel<<<(B + 3) / 4, 256, 0, stream>>>(Pq, Pk, Pv, Wo, query_words, B, 2, qb, nullptr, nullptr);

    // ent_h /= max(deg_p,1)
    norm_kernel<<<(N * 16 + 255) / 256, 256, 0, stream>>>(e0, degp, N);

    // degrees (int) -> inv_sqrt
    deg_kernel<<<(E + 255) / 256, 256, 0, stream>>>(p_src, p_dst, degc, E);
    inv_kernel<<<(N + 255) / 256, 256, 0, stream>>>(degc, inv, N);

    // CSR build: scan degc -> offs/cursor
    scan_sum<<<nchunk, 256, 0, stream>>>(degc, csum, N);
    scan_blocks<<<1, 64, 0, stream>>>(csum, nchunk);
    scan_chunk<<<nchunk, 256, 0, stream>>>(degc, csum, offs, cursor, N);

    // bucket messages (overlays dead Pq/Pk/Pv)
    scatter_msgs<<<(E + 255) / 256, 256, 0, stream>>>(p_src, p_dst, p_qid, cursor, msg, E);

    // gather conv (non-atomic writes)
    gather_conv<<<(N * 32 + 255) / 256, 256, 0, stream>>>(e0, qe0, inv, offs, msg, agg, N);

    // outputs
    out_kernel<<<(B * 128 + 255) / 256, 256, 0, stream>>>(e0, agg, inv, qb, users, items, negs, (float*)d_out, B);
}

// Round 3
// 1416.669 us; speedup vs baseline: 5.3373x; 1.1122x over previous
//
#include <hip/hip_runtime.h>

typedef unsigned int uint;
typedef unsigned short ushort;

__device__ __forceinline__ float bf2f(ushort u) {
    return __uint_as_float(((uint)u) << 16);
}
__device__ __forceinline__ float2 bfp2f(uint u) {
    float2 r;
    r.x = __uint_as_float(u << 16);
    r.y = __uint_as_float(u & 0xffff0000u);
    return r;
}
__device__ __forceinline__ ushort f2bf(float f) {
    uint u = __float_as_uint(f);
    return (ushort)((u + 0x7fffu + ((u >> 16) & 1u)) >> 16);  // RNE
}

// ---------------------------------------------------------------------------
// Pq/Pk/Pv = W_word @ {Wq,Wk,Wv} -> bf16 (one wave per row; lane = out col)
// ---------------------------------------------------------------------------
__global__ void proj_kernel(const float* __restrict__ W_word,
                            const float* __restrict__ Wq,
                            const float* __restrict__ Wk,
                            const float* __restrict__ Wv,
                            ushort* __restrict__ Pq, ushort* __restrict__ Pk,
                            ushort* __restrict__ Pv, int nrows) {
    int wid  = (blockIdx.x * blockDim.x + threadIdx.x) >> 6;
    int lane = threadIdx.x & 63;
    if (wid >= nrows) return;
    float x = W_word[(size_t)wid * 64 + lane];
    float aq = 0.f, ak = 0.f, av = 0.f;
#pragma unroll
    for (int i = 0; i < 64; i++) {
        float xi = __shfl(x, i, 64);
        aq = fmaf(xi, Wq[i * 64 + lane], aq);
        ak = fmaf(xi, Wk[i * 64 + lane], ak);
        av = fmaf(xi, Wv[i * 64 + lane], av);
    }
    size_t o = (size_t)wid * 64 + lane;
    Pq[o] = f2bf(aq); Pk[o] = f2bf(ak); Pv[o] = f2bf(av);
}

// ---------------------------------------------------------------------------
// convert f32 [rows,64] -> bf16 into low half of [rows,128] bf16 dest
// ---------------------------------------------------------------------------
__global__ void cvt_half(const float* __restrict__ src,
                         ushort* __restrict__ dst, int rows) {
    int t = blockIdx.x * blockDim.x + threadIdx.x;
    if (t >= rows * 16) return;
    int r = t >> 4, c = (t & 15) * 4;
    const float4 v = *(const float4*)(src + (size_t)r * 64 + c);
    ushort4 o;
    o.x = f2bf(v.x); o.y = f2bf(v.y); o.z = f2bf(v.z); o.w = f2bf(v.w);
    *(ushort4*)(dst + (size_t)r * 128 + c) = o;
}

// ---------------------------------------------------------------------------
// MHSA + mean over L=8, fused @Wo. One wave per sequence; lane = col.
// mode 0: outb[wid*128+64+lane] (qe0b high half, bf16)
// mode 1: outb[wid*64+lane]     (hrev, bf16)
// mode 2: outf[wid*64+lane]     (qb, f32)
// ---------------------------------------------------------------------------
__global__ void mhsa_kernel(const ushort* __restrict__ Pq,
                            const ushort* __restrict__ Pk,
                            const ushort* __restrict__ Pv,
                            const float* __restrict__ Wo,
                            const int* __restrict__ ids, int nseq, int mode,
                            ushort* __restrict__ outb,
                            float* __restrict__ outf) {
    int wid  = (blockIdx.x * blockDim.x + threadIdx.x) >> 6;
    int lane = threadIdx.x & 63;
    if (wid >= nseq) return;
    const int* idr = ids + (size_t)wid * 8;
    float qr[8], kr[8], vr[8];
#pragma unroll
    for (int l = 0; l < 8; l++) {
        int id = idr[l];
        size_t o = (size_t)id * 64 + lane;
        qr[l] = bf2f(Pq[o]); kr[l] = bf2f(Pk[o]); vr[l] = bf2f(Pv[o]);
    }
    float wacc[8] = {0.f, 0.f, 0.f, 0.f, 0.f, 0.f, 0.f, 0.f};
#pragma unroll
    for (int l = 0; l < 8; l++) {
        float sc[8];
#pragma unroll
        for (int m = 0; m < 8; m++) {
            float p = qr[l] * kr[m];
            p += __shfl_xor(p, 8, 16);
            p += __shfl_xor(p, 4, 16);
            p += __shfl_xor(p, 2, 16);
            p += __shfl_xor(p, 1, 16);
            sc[m] = p * 0.25f;
        }
        float mx = sc[0];
#pragma unroll
        for (int m = 1; m < 8; m++) mx = fmaxf(mx, sc[m]);
        float ex[8]; float sum = 0.f;
#pragma unroll
        for (int m = 0; m < 8; m++) { ex[m] = __expf(sc[m] - mx); sum += ex[m]; }
        float f = 0.125f / sum;
#pragma unroll
        for (int m = 0; m < 8; m++) wacc[m] = fmaf(ex[m], f, wacc[m]);
    }
    float om = 0.f;
#pragma unroll
    for (int m = 0; m < 8; m++) om = fmaf(wacc[m], vr[m], om);
    float h = 0.f;
#pragma unroll
    for (int i = 0; i < 64; i++) {
        float oi = __shfl(om, i, 64);
        h = fmaf(oi, Wo[i * 64 + lane], h);
    }
    if (mode == 0)      outb[(size_t)wid * 128 + 64 + lane] = f2bf(h);
    else if (mode == 1) outb[(size_t)wid * 64 + lane] = f2bf(h);
    else                outf[(size_t)wid * 64 + lane] = h;
}

// ---------------------------------------------------------------------------
// degree counts: edges (both endpoints) + review->entity counts, one pass
// ---------------------------------------------------------------------------
__global__ void count_kernel(const int* __restrict__ p_src,
                             const int* __restrict__ p_dst,
                             const int* __restrict__ profile_dst,
                             int* __restrict__ degc, int* __restrict__ degp,
                             int E, int R) {
    int t = blockIdx.x * blockDim.x + threadIdx.x;
    if (t < E) {
        atomicAdd(&degc[p_src[t]], 1);
        atomicAdd(&degc[p_dst[t]], 1);
    }
    if (t < R) atomicAdd(&degp[profile_dst[t]], 1);
}

__global__ void inv_kernel(const int* __restrict__ degc,
                           float* __restrict__ inv, int N) {
    int t = blockIdx.x * blockDim.x + threadIdx.x;
    if (t >= N) return;
    inv[t] = 1.0f / sqrtf((float)max(degc[t], 1));
}

// ---------------------------------------------------------------------------
// prefix scan (1024-chunks): deg -> offs (exclusive) + cursor copy
// ---------------------------------------------------------------------------
__global__ void scan_sum(const int* __restrict__ deg, int* __restrict__ csum,
                         int N) {
    __shared__ int red[4];
    int chunk = blockIdx.x, t = threadIdx.x;
    int base = chunk * 1024;
    int v = 0;
#pragma unroll
    for (int k = 0; k < 4; k++) {
        int idx = base + t * 4 + k;
        if (idx < N) v += deg[idx];
    }
#pragma unroll
    for (int o = 32; o; o >>= 1) v += __shfl_down(v, o, 64);
    if ((t & 63) == 0) red[t >> 6] = v;
    __syncthreads();
    if (t == 0) csum[chunk] = red[0] + red[1] + red[2] + red[3];
}

__global__ void scan_blocks(int* __restrict__ csum, int nchunk) {
    if (threadIdx.x == 0 && blockIdx.x == 0) {
        int a = 0;
        for (int i = 0; i < nchunk; i++) { int v = csum[i]; csum[i] = a; a += v; }
    }
}

__global__ void scan_chunk(const int* __restrict__ deg,
                           const int* __restrict__ csum,
                           int* __restrict__ offs, int* __restrict__ cursor,
                           int N) {
    __shared__ int lds[256];
    int chunk = blockIdx.x, t = threadIdx.x;
    int base = chunk * 1024 + t * 4;
    int v0 = (base + 0 < N) ? deg[base + 0] : 0;
    int v1 = (base + 1 < N) ? deg[base + 1] : 0;
    int v2 = (base + 2 < N) ? deg[base + 2] : 0;
    int v3 = (base + 3 < N) ? deg[base + 3] : 0;
    int s = v0 + v1 + v2 + v3;
    lds[t] = s;
    __syncthreads();
    for (int o = 1; o < 256; o <<= 1) {
        int u = (t >= o) ? lds[t - o] : 0;
        __syncthreads();
        lds[t] += u;
        __syncthreads();
    }
    int tb = lds[t] - s + csum[chunk];
    int vv[4] = {v0, v1, v2, v3};
#pragma unroll
    for (int k = 0; k < 4; k++) {
        int idx = base + k;
        if (idx < N) {
            offs[idx] = tb; cursor[idx] = tb; tb += vv[k];
            if (idx == N - 1) offs[N] = tb;
        }
    }
}

// ---------------------------------------------------------------------------
// bucket review indices by entity
// ---------------------------------------------------------------------------
__global__ void scatter_rev(const int* __restrict__ profile_dst,
                            int* __restrict__ cursor_r,
                            int* __restrict__ rmsg, int R) {
    int r = blockIdx.x * blockDim.x + threadIdx.x;
    if (r >= R) return;
    int d = profile_dst[r];
    rmsg[atomicAdd(&cursor_r[d], 1)] = r;
}

// ---------------------------------------------------------------------------
// ent_h = segment_mean(hrev) -> e0b high half (bf16). 16 lanes/entity.
// ---------------------------------------------------------------------------
__global__ void entity_gather(const ushort* __restrict__ hrev,
                              const int* __restrict__ offs_r,
                              const int* __restrict__ rmsg,
                              ushort* __restrict__ e0b, int N) {
    int g = (blockIdx.x * blockDim.x + threadIdx.x) >> 4;
    int c = (threadIdx.x & 15) * 4;
    if (g >= N) return;
    int beg = offs_r[g], end = offs_r[g + 1];
    float a0 = 0.f, a1 = 0.f, a2 = 0.f, a3 = 0.f;
    for (int m = beg; m < end; m++) {
        int r = rmsg[m];
        ushort4 v = *(const ushort4*)(hrev + (size_t)r * 64 + c);
        a0 += bf2f(v.x); a1 += bf2f(v.y); a2 += bf2f(v.z); a3 += bf2f(v.w);
    }
    float s = 1.0f / (float)max(end - beg, 1);
    ushort4 o;
    o.x = f2bf(a0 * s); o.y = f2bf(a1 * s); o.z = f2bf(a2 * s); o.w = f2bf(a3 * s);
    *(ushort4*)(e0b + (size_t)g * 128 + 64 + c) = o;
}

// ---------------------------------------------------------------------------
// bucket conv messages (8B payload, int cursor atomics)
// ---------------------------------------------------------------------------
__global__ void scatter_msgs(const int* __restrict__ p_src,
                             const int* __restrict__ p_dst,
                             const int* __restrict__ p_qid,
                             int* __restrict__ cursor, int2* __restrict__ msg,
                             int E) {
    int e = blockIdx.x * blockDim.x + threadIdx.x;
    if (e >= E) return;
    int s = p_src[e], d = p_dst[e], q = p_qid[e];
    msg[atomicAdd(&cursor[d], 1)] = make_int2(s, q);
    msg[atomicAdd(&cursor[s], 1)] = make_int2(d, -1);
}

// ---------------------------------------------------------------------------
// CSR conv gather (bf16 inputs, f32 accum): 16 lanes/node, 8 cols/lane
// ---------------------------------------------------------------------------
__global__ void gather_conv(const ushort* __restrict__ e0b,
                            const ushort* __restrict__ qe0b,
                            const float* __restrict__ inv,
                            const int* __restrict__ offs,
                            const int2* __restrict__ msg,
                            float* __restrict__ agg, int N) {
    int g = (blockIdx.x * blockDim.x + threadIdx.x) >> 4;
    int c = (threadIdx.x & 15) * 8;
    if (g >= N) return;
    int beg = offs[g], end = offs[g + 1];
    float a0 = 0.f, a1 = 0.f, a2 = 0.f, a3 = 0.f;
    float a4 = 0.f, a5 = 0.f, a6 = 0.f, a7 = 0.f;
    for (int m = beg; m < end; m++) {
        int2 mm = msg[m];
        float w = inv[mm.x];
        const uint4 ev = *(const uint4*)(e0b + (size_t)mm.x * 128 + c);
        if (mm.y >= 0) {
            const uint4 qv = *(const uint4*)(qe0b + (size_t)mm.y * 128 + c);
            float2 e, q;
            e = bfp2f(ev.x); q = bfp2f(qv.x); a0 += fmaf(q.x, w, e.x); a1 += fmaf(q.y, w, e.y);
            e = bfp2f(ev.y); q = bfp2f(qv.y); a2 += fmaf(q.x, w, e.x); a3 += fmaf(q.y, w, e.y);
            e = bfp2f(ev.z); q = bfp2f(qv.z); a4 += fmaf(q.x, w, e.x); a5 += fmaf(q.y, w, e.y);
            e = bfp2f(ev.w); q = bfp2f(qv.w); a6 += fmaf(q.x, w, e.x); a7 += fmaf(q.y, w, e.y);
        } else {
            float2 e;
            e = bfp2f(ev.x); a0 = fmaf(e.x, w, a0); a1 = fmaf(e.y, w, a1);
            e = bfp2f(ev.y); a2 = fmaf(e.x, w, a2); a3 = fmaf(e.y, w, a3);
            e = bfp2f(ev.z); a4 = fmaf(e.x, w, a4); a5 = fmaf(e.y, w, a5);
            e = bfp2f(ev.w); a6 = fmaf(e.x, w, a6); a7 = fmaf(e.y, w, a7);
        }
    }
    float4 r0; r0.x = a0; r0.y = a1; r0.z = a2; r0.w = a3;
    float4 r1; r1.x = a4; r1.y = a5; r1.z = a6; r1.w = a7;
    float* dst = agg + (size_t)g * 128 + c;
    *(float4*)dst = r0;
    *(float4*)(dst + 4) = r1;
}

// ---------------------------------------------------------------------------
// final: e(n,c) = 0.5*(e0b + agg*inv); 3 output blocks
// ---------------------------------------------------------------------------
__global__ void out_kernel(const ushort* __restrict__ e0b,
                           const float* __restrict__ agg,
                           const float* __restrict__ inv,
                           const float* __restrict__ qb,
                           const int* __restrict__ users,
                           const int* __restrict__ items,
                           const int* __restrict__ negs,
                           float* __restrict__ out, int B) {
    int t = blockIdx.x * blockDim.x + threadIdx.x;
    if (t >= B * 128) return;
    int b = t >> 7, c = t & 127;
    int u = users[b], it = items[b], ng = negs[b];
    size_t ou = (size_t)u * 128 + c, oi = (size_t)it * 128 + c, on = (size_t)ng * 128 + c;
    float eu = 0.5f * fmaf(agg[ou], inv[u], bf2f(e0b[ou]));
    float ei = 0.5f * fmaf(agg[oi], inv[it], bf2f(e0b[oi]));
    float en = 0.5f * fmaf(agg[on], inv[ng], bf2f(e0b[on]));
    float q = (c >= 64) ? qb[(size_t)b * 64 + (c - 64)] : 0.0f;
    out[t] = eu + q;
    out[(size_t)B * 128 + t] = ei;
    out[(size_t)B * 256 + t] = en;
}

// ---------------------------------------------------------------------------
extern "C" void kernel_launch(void* const* d_in, const int* in_sizes, int n_in,
                              void* d_out, int out_size, void* d_ws, size_t ws_size,
                              hipStream_t stream) {
    const float* W_word   = (const float*)d_in[0];
    const float* W_query  = (const float*)d_in[1];
    const float* W_entity = (const float*)d_in[2];
    const float* Wq       = (const float*)d_in[3];
    const float* Wk       = (const float*)d_in[4];
    const float* Wv       = (const float*)d_in[5];
    const float* Wo       = (const float*)d_in[6];
    const int* query_word_ids  = (const int*)d_in[7];
    const int* review_word_ids = (const int*)d_in[8];
    const int* profile_dst     = (const int*)d_in[9];
    const int* p_src  = (const int*)d_in[10];
    const int* p_dst  = (const int*)d_in[11];
    const int* p_qid  = (const int*)d_in[12];
    const int* users  = (const int*)d_in[13];
    const int* items  = (const int*)d_in[14];
    const int* negs   = (const int*)d_in[15];
    const int* query_words = (const int*)d_in[16];

    const int WORD = in_sizes[0] / 64;   // 50000
    const int Qn   = in_sizes[1] / 64;   // 50000
    const int N    = in_sizes[2] / 64;   // 100000
    const int R    = in_sizes[8] / 8;    // 100000
    const int E    = in_sizes[10];       // 2000000
    const int B    = in_sizes[13];       // 1024

    float*  agg  = (float*)d_ws;                        // [N,128] f32
    ushort* e0b  = (ushort*)(agg + (size_t)N * 128);    // [N,128] bf16
    ushort* qe0b = e0b + (size_t)N * 128;               // [Qn,128] bf16
    ushort* Pq   = qe0b + (size_t)Qn * 128;             // [WORD,64] bf16
    ushort* Pk   = Pq + (size_t)WORD * 64;
    ushort* Pv   = Pk + (size_t)WORD * 64;
    ushort* hrev = Pv + (size_t)WORD * 64;              // [R,64] bf16
    float*  qb   = (float*)(hrev + (size_t)R * 64);     // [B,64] f32
    float*  inv  = qb + (size_t)B * 64;                 // [N]
    int* degc     = (int*)(inv + N);                    // [N]
    int* degp     = degc + N;                           // [N]
    int* offs     = degp + N;                           // [N+2]
    int* cursor   = offs + N + 2;                       // [N]
    int* offs_r   = cursor + N;                         // [N+2]
    int* cursor_r = offs_r + N + 2;                     // [N]
    int* csum     = cursor_r + N;                       // [256]
    int* csum2    = csum + 256;                         // [256]
    int* rmsg     = csum2 + 256;                        // [R]
    int2* msg     = (int2*)(rmsg + R);                  // [2E] 8B

    const int nchunk = (N + 1023) / 1024;

    // zero degc + degp (contiguous)
    hipMemsetAsync(degc, 0, 2 * (size_t)N * sizeof(int), stream);

    // word projections (bf16)
    proj_kernel<<<(WORD + 3) / 4, 256, 0, stream>>>(W_word, Wq, Wk, Wv, Pq, Pk, Pv, WORD);

    // low halves (bf16)
    cvt_half<<<(Qn * 16 + 255) / 256, 256, 0, stream>>>(W_query, qe0b, Qn);
    cvt_half<<<(N * 16 + 255) / 256, 256, 0, stream>>>(W_entity, e0b, N);

    // MHSA passes
    mhsa_kernel<<<(Qn + 3) / 4, 256, 0, stream>>>(Pq, Pk, Pv, Wo, query_word_ids, Qn, 0, qe0b, nullptr);
    mhsa_kernel<<<(R + 3) / 4, 256, 0, stream>>>(Pq, Pk, Pv, Wo, review_word_ids, R, 1, hrev, nullptr);
    mhsa_kernel<<<(B + 3) / 4, 256, 0, stream>>>(Pq, Pk, Pv, Wo, query_words, B, 2, nullptr, qb);

    // degrees
    count_kernel<<<(max(E, R) + 255) / 256, 256, 0, stream>>>(p_src, p_dst, profile_dst, degc, degp, E, R);
    inv_kernel<<<(N + 255) / 256, 256, 0, stream>>>(degc, inv, N);

    // CSR scans (conv + reviews)
    scan_sum<<<nchunk, 256, 0, stream>>>(degc, csum, N);
    scan_blocks<<<1, 64, 0, stream>>>(csum, nchunk);
    scan_chunk<<<nchunk, 256, 0, stream>>>(degc, csum, offs, cursor, N);
    scan_sum<<<nchunk, 256, 0, stream>>>(degp, csum2, N);
    scan_blocks<<<1, 64, 0, stream>>>(csum2, nchunk);
    scan_chunk<<<nchunk, 256, 0, stream>>>(degp, csum2, offs_r, cursor_r, N);

    // review buckets -> ent_h (e0b high half)
    scatter_rev<<<(R + 255) / 256, 256, 0, stream>>>(profile_dst, cursor_r, rmsg, R);
    entity_gather<<<(N * 16 + 255) / 256, 256, 0, stream>>>(hrev, offs_r, rmsg, e0b, N);

    // conv message buckets
    scatter_msgs<<<(E + 255) / 256, 256, 0, stream>>>(p_src, p_dst, p_qid, cursor, msg, E);

    // conv gather (non-atomic writes)
    gather_conv<<<(N * 16 + 255) / 256, 256, 0, stream>>>(e0b, qe0b, inv, offs, msg, agg, N);

    // outputs
    out_kernel<<<(B * 128 + 255) / 256, 256, 0, stream>>>(e0b, agg, inv, qb, users, items, negs, (float*)d_out, B);
}

// Round 4
// 1100.736 us; speedup vs baseline: 6.8692x; 1.2870x over previous
//
#include <hip/hip_runtime.h>

typedef unsigned int uint;
typedef unsigned short ushort;

__device__ __forceinline__ float bf2f(ushort u) {
    return __uint_as_float(((uint)u) << 16);
}
__device__ __forceinline__ float2 bfp2f(uint u) {
    float2 r;
    r.x = __uint_as_float(u << 16);
    r.y = __uint_as_float(u & 0xffff0000u);
    return r;
}
__device__ __forceinline__ ushort f2bf(float f) {
    uint u = __float_as_uint(f);
    return (ushort)((u + 0x7fffu + ((u >> 16) & 1u)) >> 16);  // RNE
}

// ---------------------------------------------------------------------------
// PRE kernel: fuses (a) degree counting (atomic-latency-bound) with
// (b) proj + f32->bf16 low-half converts (VALU/mem-bound).
// Type stripe by (bid>>3)&3 so all XCDs get both kinds.
// ---------------------------------------------------------------------------
__global__ void pre_kernel(const float* __restrict__ W_word,
                           const float* __restrict__ Wq,
                           const float* __restrict__ Wk,
                           const float* __restrict__ Wv,
                           ushort* __restrict__ Pq, ushort* __restrict__ Pk,
                           ushort* __restrict__ Pv,
                           const float* __restrict__ W_query,
                           const float* __restrict__ W_entity,
                           ushort* __restrict__ qe0b, ushort* __restrict__ e0b,
                           const int* __restrict__ p_src,
                           const int* __restrict__ p_dst,
                           const int* __restrict__ profile_dst,
                           int* __restrict__ degc, int* __restrict__ degp,
                           int WORD, int Qn, int N, int E, int R,
                           int nc_blk, int npj_blk, int ncq_blk, int nce_blk) {
    int bid = blockIdx.x;
    int g = bid >> 3, j = bid & 7;
    if ((g & 3) == 3) {                       // count family
        int idx = (g >> 2) * 8 + j;
        if (idx >= nc_blk) return;
        int t = idx * 256 + threadIdx.x;
        if (t < E) {
            atomicAdd(&degc[p_src[t]], 1);
            atomicAdd(&degc[p_dst[t]], 1);
        }
        if (t < R) atomicAdd(&degp[profile_dst[t]], 1);
        return;
    }
    int idx = ((g >> 2) * 3 + (g & 3)) * 8 + j;
    if (idx < npj_blk) {
        // proj: Pq/Pk/Pv = W_word @ {Wq,Wk,Wv}; 4 rows/block, wave/row
        int wid  = idx * 4 + (threadIdx.x >> 6);
        int lane = threadIdx.x & 63;
        if (wid >= WORD) return;
        float x = W_word[(size_t)wid * 64 + lane];
        float aq = 0.f, ak = 0.f, av = 0.f;
#pragma unroll
        for (int i = 0; i < 64; i++) {
            float xi = __shfl(x, i, 64);
            aq = fmaf(xi, Wq[i * 64 + lane], aq);
            ak = fmaf(xi, Wk[i * 64 + lane], ak);
            av = fmaf(xi, Wv[i * 64 + lane], av);
        }
        size_t o = (size_t)wid * 64 + lane;
        Pq[o] = f2bf(aq); Pk[o] = f2bf(ak); Pv[o] = f2bf(av);
    } else if (idx < npj_blk + ncq_blk) {
        // cvt W_query -> qe0b low half
        int t = (idx - npj_blk) * 256 + threadIdx.x;
        if (t >= Qn * 16) return;
        int r = t >> 4, c = (t & 15) * 4;
        const float4 v = *(const float4*)(W_query + (size_t)r * 64 + c);
        ushort4 o;
        o.x = f2bf(v.x); o.y = f2bf(v.y); o.z = f2bf(v.z); o.w = f2bf(v.w);
        *(ushort4*)(qe0b + (size_t)r * 128 + c) = o;
    } else if (idx < npj_blk + ncq_blk + nce_blk) {
        // cvt W_entity -> e0b low half
        int t = (idx - npj_blk - ncq_blk) * 256 + threadIdx.x;
        if (t >= N * 16) return;
        int r = t >> 4, c = (t & 15) * 4;
        const float4 v = *(const float4*)(W_entity + (size_t)r * 64 + c);
        ushort4 o;
        o.x = f2bf(v.x); o.y = f2bf(v.y); o.z = f2bf(v.z); o.w = f2bf(v.w);
        *(ushort4*)(e0b + (size_t)r * 128 + c) = o;
    }
}

// ---------------------------------------------------------------------------
// fused prefix scans for degc and degp (1024-elem chunks)
// ---------------------------------------------------------------------------
__global__ void scan_sum2(const int* __restrict__ degc,
                          const int* __restrict__ degp,
                          int* __restrict__ csum, int* __restrict__ csum2,
                          int N, int nchunk) {
    __shared__ int red[4];
    int arr = blockIdx.x >= nchunk;
    const int* deg = arr ? degp : degc;
    int* cs = arr ? csum2 : csum;
    int chunk = arr ? blockIdx.x - nchunk : blockIdx.x;
    int t = threadIdx.x;
    int base = chunk * 1024;
    int v = 0;
#pragma unroll
    for (int k = 0; k < 4; k++) {
        int idx = base + t * 4 + k;
        if (idx < N) v += deg[idx];
    }
#pragma unroll
    for (int o = 32; o; o >>= 1) v += __shfl_down(v, o, 64);
    if ((t & 63) == 0) red[t >> 6] = v;
    __syncthreads();
    if (t == 0) cs[chunk] = red[0] + red[1] + red[2] + red[3];
}

__global__ void scan_blocks2(int* __restrict__ csum, int* __restrict__ csum2,
                             int nchunk) {
    __shared__ int lds[256];
    for (int a = 0; a < 2; a++) {
        int* cs = a ? csum2 : csum;
        int t = threadIdx.x;
        int v = (t < nchunk) ? cs[t] : 0;
        lds[t] = v;
        __syncthreads();
        for (int o = 1; o < 256; o <<= 1) {
            int u = (t >= o) ? lds[t - o] : 0;
            __syncthreads();
            lds[t] += u;
            __syncthreads();
        }
        if (t < nchunk) cs[t] = lds[t] - v;  // exclusive
        __syncthreads();
    }
}

__global__ void scan_chunk2(const int* __restrict__ degc,
                            const int* __restrict__ degp,
                            const int* __restrict__ csum,
                            const int* __restrict__ csum2,
                            int* __restrict__ offs, int* __restrict__ cursor,
                            int* __restrict__ offs_r, int* __restrict__ cursor_r,
                            float* __restrict__ inv, int N, int nchunk) {
    __shared__ int lds[256];
    int arr = blockIdx.x >= nchunk;
    const int* deg = arr ? degp : degc;
    const int* cs  = arr ? csum2 : csum;
    int* of = arr ? offs_r : offs;
    int* cu = arr ? cursor_r : cursor;
    int chunk = arr ? blockIdx.x - nchunk : blockIdx.x;
    int t = threadIdx.x;
    int base = chunk * 1024 + t * 4;
    int v0 = (base + 0 < N) ? deg[base + 0] : 0;
    int v1 = (base + 1 < N) ? deg[base + 1] : 0;
    int v2 = (base + 2 < N) ? deg[base + 2] : 0;
    int v3 = (base + 3 < N) ? deg[base + 3] : 0;
    if (!arr) {  // fold inv_sqrt of deg_i here
        if (base + 0 < N) inv[base + 0] = 1.0f / sqrtf((float)max(v0, 1));
        if (base + 1 < N) inv[base + 1] = 1.0f / sqrtf((float)max(v1, 1));
        if (base + 2 < N) inv[base + 2] = 1.0f / sqrtf((float)max(v2, 1));
        if (base + 3 < N) inv[base + 3] = 1.0f / sqrtf((float)max(v3, 1));
    }
    int s = v0 + v1 + v2 + v3;
    lds[t] = s;
    __syncthreads();
    for (int o = 1; o < 256; o <<= 1) {
        int u = (t >= o) ? lds[t - o] : 0;
        __syncthreads();
        lds[t] += u;
        __syncthreads();
    }
    int tb = lds[t] - s + cs[chunk];
    int vv[4] = {v0, v1, v2, v3};
#pragma unroll
    for (int k = 0; k < 4; k++) {
        int idx = base + k;
        if (idx < N) {
            of[idx] = tb; cu[idx] = tb; tb += vv[k];
            if (idx == N - 1) of[N] = tb;
        }
    }
}

// ---------------------------------------------------------------------------
// MHSA sequence body (wave = one sequence)
// ---------------------------------------------------------------------------
__device__ __forceinline__ void mhsa_seq(const ushort* __restrict__ Pq,
                                         const ushort* __restrict__ Pk,
                                         const ushort* __restrict__ Pv,
                                         const float* __restrict__ Wo,
                                         const int* __restrict__ ids,
                                         int wid, int lane, int mode,
                                         ushort* __restrict__ outb,
                                         float* __restrict__ outf) {
    const int* idr = ids + (size_t)wid * 8;
    float qr[8], kr[8], vr[8];
#pragma unroll
    for (int l = 0; l < 8; l++) {
        int id = idr[l];
        size_t o = (size_t)id * 64 + lane;
        qr[l] = bf2f(Pq[o]); kr[l] = bf2f(Pk[o]); vr[l] = bf2f(Pv[o]);
    }
    float wacc[8] = {0.f, 0.f, 0.f, 0.f, 0.f, 0.f, 0.f, 0.f};
#pragma unroll
    for (int l = 0; l < 8; l++) {
        float sc[8];
#pragma unroll
        for (int m = 0; m < 8; m++) {
            float p = qr[l] * kr[m];
            p += __shfl_xor(p, 8, 16);
            p += __shfl_xor(p, 4, 16);
            p += __shfl_xor(p, 2, 16);
            p += __shfl_xor(p, 1, 16);
            sc[m] = p * 0.25f;
        }
        float mx = sc[0];
#pragma unroll
        for (int m = 1; m < 8; m++) mx = fmaxf(mx, sc[m]);
        float ex[8]; float sum = 0.f;
#pragma unroll
        for (int m = 0; m < 8; m++) { ex[m] = __expf(sc[m] - mx); sum += ex[m]; }
        float f = 0.125f / sum;
#pragma unroll
        for (int m = 0; m < 8; m++) wacc[m] = fmaf(ex[m], f, wacc[m]);
    }
    float om = 0.f;
#pragma unroll
    for (int m = 0; m < 8; m++) om = fmaf(wacc[m], vr[m], om);
    float h = 0.f;
#pragma unroll
    for (int i = 0; i < 64; i++) {
        float oi = __shfl(om, i, 64);
        h = fmaf(oi, Wo[i * 64 + lane], h);
    }
    if (mode == 0)      outb[(size_t)wid * 128 + 64 + lane] = f2bf(h);
    else if (mode == 1) outb[(size_t)wid * 64 + lane] = f2bf(h);
    else                outf[(size_t)wid * 64 + lane] = h;
}

// ---------------------------------------------------------------------------
// MEGA kernel: overlaps {mhsa_r, mhsa_q, mhsa_b} (VALU/LDS-bound) with
// {scatter_msgs, scatter_rev} (atomic/vmem-latency-bound).
// ---------------------------------------------------------------------------
__global__ void mega_kernel(const ushort* __restrict__ Pq,
                            const ushort* __restrict__ Pk,
                            const ushort* __restrict__ Pv,
                            const float* __restrict__ Wo,
                            const int* __restrict__ query_word_ids,
                            const int* __restrict__ review_word_ids,
                            const int* __restrict__ query_words,
                            ushort* __restrict__ qe0b,
                            ushort* __restrict__ hrev,
                            float* __restrict__ qb,
                            const int* __restrict__ p_src,
                            const int* __restrict__ p_dst,
                            const int* __restrict__ p_qid,
                            const int* __restrict__ profile_dst,
                            int* __restrict__ cursor, int2* __restrict__ msg,
                            int* __restrict__ cursor_r, int* __restrict__ rmsg,
                            int Qn, int R, int B, int E,
                            int nr_blk, int nq_blk, int nb_blk,
                            int ns_blk, int nv_blk) {
    int bid = blockIdx.x;
    int g = bid >> 3, j = bid & 7;
    if ((g & 3) == 3) {                       // scatter family
        int idx = (g >> 2) * 8 + j;
        if (idx < ns_blk) {
            int e = idx * 256 + threadIdx.x;
            if (e >= E) return;
            int s = p_src[e], d = p_dst[e], q = p_qid[e];
            msg[atomicAdd(&cursor[d], 1)] = make_int2(s, q);
            msg[atomicAdd(&cursor[s], 1)] = make_int2(d, -1);
        } else if (idx < ns_blk + nv_blk) {
            int r = (idx - ns_blk) * 256 + threadIdx.x;
            if (r >= R) return;
            rmsg[atomicAdd(&cursor_r[profile_dst[r]], 1)] = r;
        }
        return;
    }
    int idx = ((g >> 2) * 3 + (g & 3)) * 8 + j;
    int lane = threadIdx.x & 63;
    int w = threadIdx.x >> 6;
    if (idx < nr_blk) {
        int wid = idx * 4 + w;
        if (wid < R) mhsa_seq(Pq, Pk, Pv, Wo, review_word_ids, wid, lane, 1, hrev, nullptr);
    } else if (idx < nr_blk + nq_blk) {
        int wid = (idx - nr_blk) * 4 + w;
        if (wid < Qn) mhsa_seq(Pq, Pk, Pv, Wo, query_word_ids, wid, lane, 0, qe0b, nullptr);
    } else if (idx < nr_blk + nq_blk + nb_blk) {
        int wid = (idx - nr_blk - nq_blk) * 4 + w;
        if (wid < B) mhsa_seq(Pq, Pk, Pv, Wo, query_words, wid, lane, 2, nullptr, qb);
    }
}

// ---------------------------------------------------------------------------
// ent_h = segment_mean(hrev) -> e0b high half (bf16). 16 lanes/entity.
// ---------------------------------------------------------------------------
__global__ void entity_gather(const ushort* __restrict__ hrev,
                              const int* __restrict__ offs_r,
                              const int* __restrict__ rmsg,
                              ushort* __restrict__ e0b, int N) {
    int g = (blockIdx.x * blockDim.x + threadIdx.x) >> 4;
    int c = (threadIdx.x & 15) * 4;
    if (g >= N) return;
    int beg = offs_r[g], end = offs_r[g + 1];
    float a0 = 0.f, a1 = 0.f, a2 = 0.f, a3 = 0.f;
    for (int m = beg; m < end; m++) {
        int r = rmsg[m];
        ushort4 v = *(const ushort4*)(hrev + (size_t)r * 64 + c);
        a0 += bf2f(v.x); a1 += bf2f(v.y); a2 += bf2f(v.z); a3 += bf2f(v.w);
    }
    float s = 1.0f / (float)max(end - beg, 1);
    ushort4 o;
    o.x = f2bf(a0 * s); o.y = f2bf(a1 * s); o.z = f2bf(a2 * s); o.w = f2bf(a3 * s);
    *(ushort4*)(e0b + (size_t)g * 128 + 64 + c) = o;
}

// ---------------------------------------------------------------------------
// CSR conv gather (bf16 inputs, f32 accum): 16 lanes/node, 8 cols/lane
// ---------------------------------------------------------------------------
__global__ void gather_conv(const ushort* __restrict__ e0b,
                            const ushort* __restrict__ qe0b,
                            const float* __restrict__ inv,
                            const int* __restrict__ offs,
                            const int2* __restrict__ msg,
                            float* __restrict__ agg, int N) {
    int g = (blockIdx.x * blockDim.x + threadIdx.x) >> 4;
    int c = (threadIdx.x & 15) * 8;
    if (g >= N) return;
    int beg = offs[g], end = offs[g + 1];
    float a0 = 0.f, a1 = 0.f, a2 = 0.f, a3 = 0.f;
    float a4 = 0.f, a5 = 0.f, a6 = 0.f, a7 = 0.f;
    for (int m = beg; m < end; m++) {
        int2 mm = msg[m];
        float w = inv[mm.x];
        const uint4 ev = *(const uint4*)(e0b + (size_t)mm.x * 128 + c);
        if (mm.y >= 0) {
            const uint4 qv = *(const uint4*)(qe0b + (size_t)mm.y * 128 + c);
            float2 e, q;
            e = bfp2f(ev.x); q = bfp2f(qv.x); a0 += fmaf(q.x, w, e.x); a1 += fmaf(q.y, w, e.y);
            e = bfp2f(ev.y); q = bfp2f(qv.y); a2 += fmaf(q.x, w, e.x); a3 += fmaf(q.y, w, e.y);
            e = bfp2f(ev.z); q = bfp2f(qv.z); a4 += fmaf(q.x, w, e.x); a5 += fmaf(q.y, w, e.y);
            e = bfp2f(ev.w); q = bfp2f(qv.w); a6 += fmaf(q.x, w, e.x); a7 += fmaf(q.y, w, e.y);
        } else {
            float2 e;
            e = bfp2f(ev.x); a0 = fmaf(e.x, w, a0); a1 = fmaf(e.y, w, a1);
            e = bfp2f(ev.y); a2 = fmaf(e.x, w, a2); a3 = fmaf(e.y, w, a3);
            e = bfp2f(ev.z); a4 = fmaf(e.x, w, a4); a5 = fmaf(e.y, w, a5);
            e = bfp2f(ev.w); a6 = fmaf(e.x, w, a6); a7 = fmaf(e.y, w, a7);
        }
    }
    float4 r0; r0.x = a0; r0.y = a1; r0.z = a2; r0.w = a3;
    float4 r1; r1.x = a4; r1.y = a5; r1.z = a6; r1.w = a7;
    float* dst = agg + (size_t)g * 128 + c;
    *(float4*)dst = r0;
    *(float4*)(dst + 4) = r1;
}

// ---------------------------------------------------------------------------
// final: e(n,c) = 0.5*(e0b + agg*inv); 3 output blocks
// ---------------------------------------------------------------------------
__global__ void out_kernel(const ushort* __restrict__ e0b,
                           const float* __restrict__ agg,
                           const float* __restrict__ inv,
                           const float* __restrict__ qb,
                           const int* __restrict__ users,
                           const int* __restrict__ items,
                           const int* __restrict__ negs,
                           float* __restrict__ out, int B) {
    int t = blockIdx.x * blockDim.x + threadIdx.x;
    if (t >= B * 128) return;
    int b = t >> 7, c = t & 127;
    int u = users[b], it = items[b], ng = negs[b];
    size_t ou = (size_t)u * 128 + c, oi = (size_t)it * 128 + c, on = (size_t)ng * 128 + c;
    float eu = 0.5f * fmaf(agg[ou], inv[u], bf2f(e0b[ou]));
    float ei = 0.5f * fmaf(agg[oi], inv[it], bf2f(e0b[oi]));
    float en = 0.5f * fmaf(agg[on], inv[ng], bf2f(e0b[on]));
    float q = (c >= 64) ? qb[(size_t)b * 64 + (c - 64)] : 0.0f;
    out[t] = eu + q;
    out[(size_t)B * 128 + t] = ei;
    out[(size_t)B * 256 + t] = en;
}

// ---------------------------------------------------------------------------
extern "C" void kernel_launch(void* const* d_in, const int* in_sizes, int n_in,
                              void* d_out, int out_size, void* d_ws, size_t ws_size,
                              hipStream_t stream) {
    const float* W_word   = (const float*)d_in[0];
    const float* W_query  = (const float*)d_in[1];
    const float* W_entity = (const float*)d_in[2];
    const float* Wq       = (const float*)d_in[3];
    const float* Wk       = (const float*)d_in[4];
    const float* Wv       = (const float*)d_in[5];
    const float* Wo       = (const float*)d_in[6];
    const int* query_word_ids  = (const int*)d_in[7];
    const int* review_word_ids = (const int*)d_in[8];
    const int* profile_dst     = (const int*)d_in[9];
    const int* p_src  = (const int*)d_in[10];
    const int* p_dst  = (const int*)d_in[11];
    const int* p_qid  = (const int*)d_in[12];
    const int* users  = (const int*)d_in[13];
    const int* items  = (const int*)d_in[14];
    const int* negs   = (const int*)d_in[15];
    const int* query_words = (const int*)d_in[16];

    const int WORD = in_sizes[0] / 64;   // 50000
    const int Qn   = in_sizes[1] / 64;   // 50000
    const int N    = in_sizes[2] / 64;   // 100000
    const int R    = in_sizes[8] / 8;    // 100000
    const int E    = in_sizes[10];       // 2000000
    const int B    = in_sizes[13];       // 1024

    float*  agg  = (float*)d_ws;                        // [N,128] f32
    ushort* e0b  = (ushort*)(agg + (size_t)N * 128);    // [N,128] bf16
    ushort* qe0b = e0b + (size_t)N * 128;               // [Qn,128] bf16
    ushort* Pq   = qe0b + (size_t)Qn * 128;             // [WORD,64] bf16
    ushort* Pk   = Pq + (size_t)WORD * 64;
    ushort* Pv   = Pk + (size_t)WORD * 64;
    ushort* hrev = Pv + (size_t)WORD * 64;              // [R,64] bf16
    float*  qb   = (float*)(hrev + (size_t)R * 64);     // [B,64] f32
    float*  inv  = qb + (size_t)B * 64;                 // [N]
    int* degc     = (int*)(inv + N);                    // [N]
    int* degp     = degc + N;                           // [N]
    int* offs     = degp + N;                           // [N+2]
    int* cursor   = offs + N + 2;                       // [N]
    int* offs_r   = cursor + N;                         // [N+2]
    int* cursor_r = offs_r + N + 2;                     // [N]
    int* csum     = cursor_r + N;                       // [256]
    int* csum2    = csum + 256;                         // [256]
    int* rmsg     = csum2 + 256;                        // [R]
    int2* msg     = (int2*)(rmsg + R);                  // [2E] 8B

    const int nchunk = (N + 1023) / 1024;               // 98

    // zero degc + degp (contiguous)
    hipMemsetAsync(degc, 0, 2 * (size_t)N * sizeof(int), stream);

    // PRE: count + proj + cvt fused
    {
        int nc_blk  = (E + 255) / 256;
        int npj_blk = (WORD + 3) / 4;
        int ncq_blk = (Qn * 16 + 255) / 256;
        int nce_blk = (N * 16 + 255) / 256;
        int mh_fam  = npj_blk + ncq_blk + nce_blk;
        int T = max(4 * nc_blk, (mh_fam * 4 + 2) / 3);
        T = ((T + 31) / 32) * 32;
        pre_kernel<<<T, 256, 0, stream>>>(W_word, Wq, Wk, Wv, Pq, Pk, Pv,
                                          W_query, W_entity, qe0b, e0b,
                                          p_src, p_dst, profile_dst, degc, degp,
                                          WORD, Qn, N, E, R,
                                          nc_blk, npj_blk, ncq_blk, nce_blk);
    }

    // fused scans (degc -> offs/cursor/inv, degp -> offs_r/cursor_r)
    scan_sum2<<<2 * nchunk, 256, 0, stream>>>(degc, degp, csum, csum2, N, nchunk);
    scan_blocks2<<<1, 256, 0, stream>>>(csum, csum2, nchunk);
    scan_chunk2<<<2 * nchunk, 256, 0, stream>>>(degc, degp, csum, csum2,
                                                offs, cursor, offs_r, cursor_r,
                                                inv, N, nchunk);

    // MEGA: mhsa x3 + scatter_msgs + scatter_rev overlapped
    {
        int nr_blk = (R + 3) / 4;
        int nq_blk = (Qn + 3) / 4;
        int nb_blk = (B + 3) / 4;
        int ns_blk = (E + 255) / 256;
        int nv_blk = (R + 255) / 256;
        int sc_fam = ns_blk + nv_blk;
        int mg_fam = nr_blk + nq_blk + nb_blk;
        int T = max(4 * sc_fam, (mg_fam * 4 + 2) / 3);
        T = ((T + 31) / 32) * 32;
        mega_kernel<<<T, 256, 0, stream>>>(Pq, Pk, Pv, Wo,
                                           query_word_ids, review_word_ids, query_words,
                                           qe0b, hrev, qb,
                                           p_src, p_dst, p_qid, profile_dst,
                                           cursor, msg, cursor_r, rmsg,
                                           Qn, R, B, E,
                                           nr_blk, nq_blk, nb_blk, ns_blk, nv_blk);
    }

    // ent_h -> e0b high half
    entity_gather<<<(N * 16 + 255) / 256, 256, 0, stream>>>(hrev, offs_r, rmsg, e0b, N);

    // conv gather (non-atomic writes)
    gather_conv<<<(N * 16 + 255) / 256, 256, 0, stream>>>(e0b, qe0b, inv, offs, msg, agg, N);

    // outputs
    out_kernel<<<(B * 128 + 255) / 256, 256, 0, stream>>>(e0b, agg, inv, qb, users, items, negs, (float*)d_out, B);
}

// Round 5
// 751.662 us; speedup vs baseline: 10.0593x; 1.4644x over previous
//
#include <hip/hip_runtime.h>

typedef unsigned int uint;
typedef unsigned short ushort;

typedef __bf16 bf16x8 __attribute__((ext_vector_type(8)));
typedef float f32x4 __attribute__((ext_vector_type(4)));
union U8 { uint4 u4; uint w[4]; bf16x8 b; };

__device__ __forceinline__ float bf2f(ushort u) {
    return __uint_as_float(((uint)u) << 16);
}
__device__ __forceinline__ float2 bfp2f(uint u) {
    float2 r;
    r.x = __uint_as_float(u << 16);
    r.y = __uint_as_float(u & 0xffff0000u);
    return r;
}
__device__ __forceinline__ ushort f2bf(float f) {
    uint u = __float_as_uint(f);
    return (ushort)((u + 0x7fffu + ((u >> 16) & 1u)) >> 16);  // RNE
}

// ---------------------------------------------------------------------------
// PRE kernel: fuses (a) degree counting (atomic-latency-bound) with
// (b) proj (+ folded Wo -> Vt) + f32->bf16 low-half converts.
// ---------------------------------------------------------------------------
__global__ void pre_kernel(const float* __restrict__ W_word,
                           const float* __restrict__ Wq,
                           const float* __restrict__ Wk,
                           const float* __restrict__ Wv,
                           const float* __restrict__ Wo,
                           ushort* __restrict__ Pq, ushort* __restrict__ Pk,
                           ushort* __restrict__ Vt,
                           const float* __restrict__ W_query,
                           const float* __restrict__ W_entity,
                           ushort* __restrict__ qe0b, ushort* __restrict__ e0b,
                           const int* __restrict__ p_src,
                           const int* __restrict__ p_dst,
                           const int* __restrict__ profile_dst,
                           int* __restrict__ degc, int* __restrict__ degp,
                           int WORD, int Qn, int N, int E, int R,
                           int nc_blk, int npj_blk, int ncq_blk, int nce_blk) {
    int bid = blockIdx.x;
    int g = bid >> 3, j = bid & 7;
    if ((g & 3) == 3) {                       // count family
        int idx = (g >> 2) * 8 + j;
        if (idx >= nc_blk) return;
        int t = idx * 256 + threadIdx.x;
        if (t < E) {
            atomicAdd(&degc[p_src[t]], 1);
            atomicAdd(&degc[p_dst[t]], 1);
        }
        if (t < R) atomicAdd(&degp[profile_dst[t]], 1);
        return;
    }
    int idx = ((g >> 2) * 3 + (g & 3)) * 8 + j;
    if (idx < npj_blk) {
        // proj: q,k projections + Vt[w][h][:] = v_h(w) @ Wo_h
        int wid  = idx * 4 + (threadIdx.x >> 6);
        int lane = threadIdx.x & 63;
        if (wid >= WORD) return;
        float x = W_word[(size_t)wid * 64 + lane];
        float aq = 0.f, ak = 0.f, av = 0.f;
#pragma unroll
        for (int i = 0; i < 64; i++) {
            float xi = __shfl(x, i, 64);
            aq = fmaf(xi, Wq[i * 64 + lane], aq);
            ak = fmaf(xi, Wk[i * 64 + lane], ak);
            av = fmaf(xi, Wv[i * 64 + lane], av);
        }
        size_t o = (size_t)wid * 64 + lane;
        Pq[o] = f2bf(aq); Pk[o] = f2bf(ak);
        float vt[4] = {0.f, 0.f, 0.f, 0.f};
#pragma unroll
        for (int i = 0; i < 64; i++) {
            float vi = __shfl(av, i, 64);
            vt[i >> 4] = fmaf(vi, Wo[i * 64 + lane], vt[i >> 4]);
        }
#pragma unroll
        for (int h = 0; h < 4; h++)
            Vt[((size_t)wid * 4 + h) * 64 + lane] = f2bf(vt[h]);
    } else if (idx < npj_blk + ncq_blk) {
        int t = (idx - npj_blk) * 256 + threadIdx.x;
        if (t >= Qn * 16) return;
        int r = t >> 4, c = (t & 15) * 4;
        const float4 v = *(const float4*)(W_query + (size_t)r * 64 + c);
        ushort4 o;
        o.x = f2bf(v.x); o.y = f2bf(v.y); o.z = f2bf(v.z); o.w = f2bf(v.w);
        *(ushort4*)(qe0b + (size_t)r * 128 + c) = o;
    } else if (idx < npj_blk + ncq_blk + nce_blk) {
        int t = (idx - npj_blk - ncq_blk) * 256 + threadIdx.x;
        if (t >= N * 16) return;
        int r = t >> 4, c = (t & 15) * 4;
        const float4 v = *(const float4*)(W_entity + (size_t)r * 64 + c);
        ushort4 o;
        o.x = f2bf(v.x); o.y = f2bf(v.y); o.z = f2bf(v.z); o.w = f2bf(v.w);
        *(ushort4*)(e0b + (size_t)r * 128 + c) = o;
    }
}

// ---------------------------------------------------------------------------
// fused prefix scans for degc and degp (1024-elem chunks)
// ---------------------------------------------------------------------------
__global__ void scan_sum2(const int* __restrict__ degc,
                          const int* __restrict__ degp,
                          int* __restrict__ csum, int* __restrict__ csum2,
                          int N, int nchunk) {
    __shared__ int red[4];
    int arr = blockIdx.x >= nchunk;
    const int* deg = arr ? degp : degc;
    int* cs = arr ? csum2 : csum;
    int chunk = arr ? blockIdx.x - nchunk : blockIdx.x;
    int t = threadIdx.x;
    int base = chunk * 1024;
    int v = 0;
#pragma unroll
    for (int k = 0; k < 4; k++) {
        int idx = base + t * 4 + k;
        if (idx < N) v += deg[idx];
    }
#pragma unroll
    for (int o = 32; o; o >>= 1) v += __shfl_down(v, o, 64);
    if ((t & 63) == 0) red[t >> 6] = v;
    __syncthreads();
    if (t == 0) cs[chunk] = red[0] + red[1] + red[2] + red[3];
}

__global__ void scan_blocks2(int* __restrict__ csum, int* __restrict__ csum2,
                             int nchunk) {
    __shared__ int lds[256];
    for (int a = 0; a < 2; a++) {
        int* cs = a ? csum2 : csum;
        int t = threadIdx.x;
        int v = (t < nchunk) ? cs[t] : 0;
        lds[t] = v;
        __syncthreads();
        for (int o = 1; o < 256; o <<= 1) {
            int u = (t >= o) ? lds[t - o] : 0;
            __syncthreads();
            lds[t] += u;
            __syncthreads();
        }
        if (t < nchunk) cs[t] = lds[t] - v;  // exclusive
        __syncthreads();
    }
}

__global__ void scan_chunk2(const int* __restrict__ degc,
                            const int* __restrict__ degp,
                            const int* __restrict__ csum,
                            const int* __restrict__ csum2,
                            int* __restrict__ offs, int* __restrict__ cursor,
                            int* __restrict__ offs_r, int* __restrict__ cursor_r,
                            float* __restrict__ inv, int N, int nchunk) {
    __shared__ int lds[256];
    int arr = blockIdx.x >= nchunk;
    const int* deg = arr ? degp : degc;
    const int* cs  = arr ? csum2 : csum;
    int* of = arr ? offs_r : offs;
    int* cu = arr ? cursor_r : cursor;
    int chunk = arr ? blockIdx.x - nchunk : blockIdx.x;
    int t = threadIdx.x;
    int base = chunk * 1024 + t * 4;
    int v0 = (base + 0 < N) ? deg[base + 0] : 0;
    int v1 = (base + 1 < N) ? deg[base + 1] : 0;
    int v2 = (base + 2 < N) ? deg[base + 2] : 0;
    int v3 = (base + 3 < N) ? deg[base + 3] : 0;
    if (!arr) {
        if (base + 0 < N) inv[base + 0] = 1.0f / sqrtf((float)max(v0, 1));
        if (base + 1 < N) inv[base + 1] = 1.0f / sqrtf((float)max(v1, 1));
        if (base + 2 < N) inv[base + 2] = 1.0f / sqrtf((float)max(v2, 1));
        if (base + 3 < N) inv[base + 3] = 1.0f / sqrtf((float)max(v3, 1));
    }
    int s = v0 + v1 + v2 + v3;
    lds[t] = s;
    __syncthreads();
    for (int o = 1; o < 256; o <<= 1) {
        int u = (t >= o) ? lds[t - o] : 0;
        __syncthreads();
        lds[t] += u;
        __syncthreads();
    }
    int tb = lds[t] - s + cs[chunk];
    int vv[4] = {v0, v1, v2, v3};
#pragma unroll
    for (int k = 0; k < 4; k++) {
        int idx = base + k;
        if (idx < N) {
            of[idx] = tb; cu[idx] = tb; tb += vv[k];
            if (idx == N - 1) of[N] = tb;
        }
    }
}

// ---------------------------------------------------------------------------
// MFMA MHSA: one wave = TWO sequences. 16x16x32 bf16 MFMAs.
//  scores: A=K rows(m=lane&15), B=Q cols(l=lane&15), K-dim=(seq,d), invalid
//  lanes zeroed -> D[m,l] block-diagonal per seq.
//  softmax over m: in-lane 4 regs + shfl_xor 16/32.
//  PV: A'=attn bf16 (k=(hpair-bit,m)), B'=Vt (Wo pre-folded), 2 MFMA/t-tile
//  chained over head-pairs; mean over l via in-lane + shfl_xor 16.
// ---------------------------------------------------------------------------
__device__ __forceinline__ void mhsa_pair(const ushort* __restrict__ Pq,
                                          const ushort* __restrict__ Pk,
                                          const ushort* __restrict__ Vt,
                                          const int* __restrict__ ids,
                                          int wid2, int lane, int mode,
                                          ushort* __restrict__ outb,
                                          float* __restrict__ outf) {
    const int l15 = lane & 15;
    const int gi  = lane >> 4;
    const int hs  = gi >> 1;              // head-bit within pair
    const int dbase = (gi & 1) * 8;       // d-range / m'-range base
    const int* idr = ids + (size_t)wid2 * 16;
    const bool valid = hs == (l15 >> 3);  // load- and D-validity (same formula)

    const int myid = idr[l15];
    int vid[8];
#pragma unroll
    for (int i = 0; i < 8; i++) vid[i] = idr[dbase + i];

    // ---- scores + softmax per head -> packed bf16 attn (pk4[h][2]) ----
    uint pk4[4][2];
    const f32x4 zero4 = {0.f, 0.f, 0.f, 0.f};
#pragma unroll
    for (int h = 0; h < 4; h++) {
        U8 a, b;
        if (valid) {
            a.u4 = *(const uint4*)(Pk + (size_t)myid * 64 + h * 16 + dbase);
            b.u4 = *(const uint4*)(Pq + (size_t)myid * 64 + h * 16 + dbase);
        } else {
            a.u4 = make_uint4(0, 0, 0, 0);
            b.u4 = make_uint4(0, 0, 0, 0);
        }
        f32x4 d = __builtin_amdgcn_mfma_f32_16x16x32_bf16(a.b, b.b, zero4, 0, 0, 0);
        float s0 = d[0] * 0.25f, s1 = d[1] * 0.25f;
        float s2 = d[2] * 0.25f, s3 = d[3] * 0.25f;
        if (!valid) { s0 = s1 = s2 = s3 = -1e30f; }
        float mx = fmaxf(fmaxf(s0, s1), fmaxf(s2, s3));
        mx = fmaxf(mx, __shfl_xor(mx, 16, 64));
        mx = fmaxf(mx, __shfl_xor(mx, 32, 64));
        float x0 = __expf(s0 - mx), x1 = __expf(s1 - mx);
        float x2 = __expf(s2 - mx), x3 = __expf(s3 - mx);
        float sm = x0 + x1 + x2 + x3;
        sm += __shfl_xor(sm, 16, 64);
        sm += __shfl_xor(sm, 32, 64);
        float f = 0.125f / sm;            // mean over l folded in
        uint w0 = (uint)f2bf(x0 * f) | ((uint)f2bf(x1 * f) << 16);
        uint w1 = (uint)f2bf(x2 * f) | ((uint)f2bf(x3 * f) << 16);
        pk4[h][0] = valid ? w0 : 0u;
        pk4[h][1] = valid ? w1 : 0u;
    }

    // ---- redistribute attn into A' fragments (per head-pair) ----
    const int srcA = l15 + (gi & 1) * 32;
    const int srcB = srcA + 16;
    uint aw[2][4];
#pragma unroll
    for (int P = 0; P < 2; P++) {
        uint r00 = (uint)__shfl((int)pk4[2 * P][0], srcA, 64);
        uint r01 = (uint)__shfl((int)pk4[2 * P][1], srcA, 64);
        uint r02 = (uint)__shfl((int)pk4[2 * P][0], srcB, 64);
        uint r03 = (uint)__shfl((int)pk4[2 * P][1], srcB, 64);
        uint r10 = (uint)__shfl((int)pk4[2 * P + 1][0], srcA, 64);
        uint r11 = (uint)__shfl((int)pk4[2 * P + 1][1], srcA, 64);
        uint r12 = (uint)__shfl((int)pk4[2 * P + 1][0], srcB, 64);
        uint r13 = (uint)__shfl((int)pk4[2 * P + 1][1], srcB, 64);
        aw[P][0] = hs ? r10 : r00;
        aw[P][1] = hs ? r11 : r01;
        aw[P][2] = hs ? r12 : r02;
        aw[P][3] = hs ? r13 : r03;
    }

    // ---- PV per column tile, heads chained; then mean over l + store ----
    size_t vb[8];
#pragma unroll
    for (int i = 0; i < 8; i++) vb[i] = (size_t)vid[i] * 256;
#pragma unroll
    for (int t = 0; t < 4; t++) {
        const int col = t * 16 + l15;
        f32x4 acc = zero4;
#pragma unroll
        for (int P = 0; P < 2; P++) {
            const int h = 2 * P + hs;
            uint e[8];
#pragma unroll
            for (int i = 0; i < 8; i++) e[i] = Vt[vb[i] + h * 64 + col];
            U8 bv;
            bv.w[0] = e[0] | (e[1] << 16);
            bv.w[1] = e[2] | (e[3] << 16);
            bv.w[2] = e[4] | (e[5] << 16);
            bv.w[3] = e[6] | (e[7] << 16);
            U8 av_;
            av_.w[0] = aw[P][0]; av_.w[1] = aw[P][1];
            av_.w[2] = aw[P][2]; av_.w[3] = aw[P][3];
            acc = __builtin_amdgcn_mfma_f32_16x16x32_bf16(av_.b, bv.b, acc, 0, 0, 0);
        }
        float s = acc[0] + acc[1] + acc[2] + acc[3];
        s += __shfl_xor(s, 16, 64);
        if ((gi & 1) == 0) {              // gi==0 -> seq0, gi==2 -> seq1
            int row = wid2 * 2 + hs;
            if (mode == 0)      outb[(size_t)row * 128 + 64 + col] = f2bf(s);
            else if (mode == 1) outb[(size_t)row * 64 + col] = f2bf(s);
            else                outf[(size_t)row * 64 + col] = s;
        }
    }
}

// ---------------------------------------------------------------------------
// MEGA kernel: overlaps {mhsa_r, mhsa_q, mhsa_b} (MFMA/VALU-bound) with
// {scatter_msgs, scatter_rev} (atomic/vmem-latency-bound).
// ---------------------------------------------------------------------------
__global__ void mega_kernel(const ushort* __restrict__ Pq,
                            const ushort* __restrict__ Pk,
                            const ushort* __restrict__ Vt,
                            const int* __restrict__ query_word_ids,
                            const int* __restrict__ review_word_ids,
                            const int* __restrict__ query_words,
                            ushort* __restrict__ qe0b,
                            ushort* __restrict__ hrev,
                            float* __restrict__ qb,
                            const int* __restrict__ p_src,
                            const int* __restrict__ p_dst,
                            const int* __restrict__ p_qid,
                            const int* __restrict__ profile_dst,
                            int* __restrict__ cursor, int2* __restrict__ msg,
                            int* __restrict__ cursor_r, int* __restrict__ rmsg,
                            int Qn, int R, int B, int E,
                            int nr_blk, int nq_blk, int nb_blk,
                            int ns_blk, int nv_blk) {
    int bid = blockIdx.x;
    int g = bid >> 3, j = bid & 7;
    if ((g & 3) == 3) {                       // scatter family
        int idx = (g >> 2) * 8 + j;
        if (idx < ns_blk) {
            int e = idx * 256 + threadIdx.x;
            if (e >= E) return;
            int s = p_src[e], d = p_dst[e], q = p_qid[e];
            msg[atomicAdd(&cursor[d], 1)] = make_int2(s, q);
            msg[atomicAdd(&cursor[s], 1)] = make_int2(d, -1);
        } else if (idx < ns_blk + nv_blk) {
            int r = (idx - ns_blk) * 256 + threadIdx.x;
            if (r >= R) return;
            rmsg[atomicAdd(&cursor_r[profile_dst[r]], 1)] = r;
        }
        return;
    }
    int idx = ((g >> 2) * 3 + (g & 3)) * 8 + j;
    int lane = threadIdx.x & 63;
    int w = threadIdx.x >> 6;
    if (idx < nr_blk) {
        int wid2 = idx * 4 + w;
        if (wid2 < (R >> 1))
            mhsa_pair(Pq, Pk, Vt, review_word_ids, wid2, lane, 1, hrev, nullptr);
    } else if (idx < nr_blk + nq_blk) {
        int wid2 = (idx - nr_blk) * 4 + w;
        if (wid2 < (Qn >> 1))
            mhsa_pair(Pq, Pk, Vt, query_word_ids, wid2, lane, 0, qe0b, nullptr);
    } else if (idx < nr_blk + nq_blk + nb_blk) {
        int wid2 = (idx - nr_blk - nq_blk) * 4 + w;
        if (wid2 < (B >> 1))
            mhsa_pair(Pq, Pk, Vt, query_words, wid2, lane, 2, nullptr, qb);
    }
}

// ---------------------------------------------------------------------------
// ent_h = segment_mean(hrev) -> e0b high half (bf16). 16 lanes/entity.
// ---------------------------------------------------------------------------
__global__ void entity_gather(const ushort* __restrict__ hrev,
                              const int* __restrict__ offs_r,
                              const int* __restrict__ rmsg,
                              ushort* __restrict__ e0b, int N) {
    int g = (blockIdx.x * blockDim.x + threadIdx.x) >> 4;
    int c = (threadIdx.x & 15) * 4;
    if (g >= N) return;
    int beg = offs_r[g], end = offs_r[g + 1];
    float a0 = 0.f, a1 = 0.f, a2 = 0.f, a3 = 0.f;
    for (int m = beg; m < end; m++) {
        int r = rmsg[m];
        ushort4 v = *(const ushort4*)(hrev + (size_t)r * 64 + c);
        a0 += bf2f(v.x); a1 += bf2f(v.y); a2 += bf2f(v.z); a3 += bf2f(v.w);
    }
    float s = 1.0f / (float)max(end - beg, 1);
    ushort4 o;
    o.x = f2bf(a0 * s); o.y = f2bf(a1 * s); o.z = f2bf(a2 * s); o.w = f2bf(a3 * s);
    *(ushort4*)(e0b + (size_t)g * 128 + 64 + c) = o;
}

// ---------------------------------------------------------------------------
// CSR conv gather (bf16 inputs, f32 accum): 16 lanes/node, 8 cols/lane
// ---------------------------------------------------------------------------
__global__ void gather_conv(const ushort* __restrict__ e0b,
                            const ushort* __restrict__ qe0b,
                            const float* __restrict__ inv,
                            const int* __restrict__ offs,
                            const int2* __restrict__ msg,
                            float* __restrict__ agg, int N) {
    int g = (blockIdx.x * blockDim.x + threadIdx.x) >> 4;
    int c = (threadIdx.x & 15) * 8;
    if (g >= N) return;
    int beg = offs[g], end = offs[g + 1];
    float a0 = 0.f, a1 = 0.f, a2 = 0.f, a3 = 0.f;
    float a4 = 0.f, a5 = 0.f, a6 = 0.f, a7 = 0.f;
    for (int m = beg; m < end; m++) {
        int2 mm = msg[m];
        float w = inv[mm.x];
        const uint4 ev = *(const uint4*)(e0b + (size_t)mm.x * 128 + c);
        if (mm.y >= 0) {
            const uint4 qv = *(const uint4*)(qe0b + (size_t)mm.y * 128 + c);
            float2 e, q;
            e = bfp2f(ev.x); q = bfp2f(qv.x); a0 += fmaf(q.x, w, e.x); a1 += fmaf(q.y, w, e.y);
            e = bfp2f(ev.y); q = bfp2f(qv.y); a2 += fmaf(q.x, w, e.x); a3 += fmaf(q.y, w, e.y);
            e = bfp2f(ev.z); q = bfp2f(qv.z); a4 += fmaf(q.x, w, e.x); a5 += fmaf(q.y, w, e.y);
            e = bfp2f(ev.w); q = bfp2f(qv.w); a6 += fmaf(q.x, w, e.x); a7 += fmaf(q.y, w, e.y);
        } else {
            float2 e;
            e = bfp2f(ev.x); a0 = fmaf(e.x, w, a0); a1 = fmaf(e.y, w, a1);
            e = bfp2f(ev.y); a2 = fmaf(e.x, w, a2); a3 = fmaf(e.y, w, a3);
            e = bfp2f(ev.z); a4 = fmaf(e.x, w, a4); a5 = fmaf(e.y, w, a5);
            e = bfp2f(ev.w); a6 = fmaf(e.x, w, a6); a7 = fmaf(e.y, w, a7);
        }
    }
    float4 r0; r0.x = a0; r0.y = a1; r0.z = a2; r0.w = a3;
    float4 r1; r1.x = a4; r1.y = a5; r1.z = a6; r1.w = a7;
    float* dst = agg + (size_t)g * 128 + c;
    *(float4*)dst = r0;
    *(float4*)(dst + 4) = r1;
}

// ---------------------------------------------------------------------------
// final: e(n,c) = 0.5*(e0b + agg*inv); 3 output blocks
// ---------------------------------------------------------------------------
__global__ void out_kernel(const ushort* __restrict__ e0b,
                           const float* __restrict__ agg,
                           const float* __restrict__ inv,
                           const float* __restrict__ qb,
                           const int* __restrict__ users,
                           const int* __restrict__ items,
                           const int* __restrict__ negs,
                           float* __restrict__ out, int B) {
    int t = blockIdx.x * blockDim.x + threadIdx.x;
    if (t >= B * 128) return;
    int b = t >> 7, c = t & 127;
    int u = users[b], it = items[b], ng = negs[b];
    size_t ou = (size_t)u * 128 + c, oi = (size_t)it * 128 + c, on = (size_t)ng * 128 + c;
    float eu = 0.5f * fmaf(agg[ou], inv[u], bf2f(e0b[ou]));
    float ei = 0.5f * fmaf(agg[oi], inv[it], bf2f(e0b[oi]));
    float en = 0.5f * fmaf(agg[on], inv[ng], bf2f(e0b[on]));
    float q = (c >= 64) ? qb[(size_t)b * 64 + (c - 64)] : 0.0f;
    out[t] = eu + q;
    out[(size_t)B * 128 + t] = ei;
    out[(size_t)B * 256 + t] = en;
}

// ---------------------------------------------------------------------------
extern "C" void kernel_launch(void* const* d_in, const int* in_sizes, int n_in,
                              void* d_out, int out_size, void* d_ws, size_t ws_size,
                              hipStream_t stream) {
    const float* W_word   = (const float*)d_in[0];
    const float* W_query  = (const float*)d_in[1];
    const float* W_entity = (const float*)d_in[2];
    const float* Wq       = (const float*)d_in[3];
    const float* Wk       = (const float*)d_in[4];
    const float* Wv       = (const float*)d_in[5];
    const float* Wo       = (const float*)d_in[6];
    const int* query_word_ids  = (const int*)d_in[7];
    const int* review_word_ids = (const int*)d_in[8];
    const int* profile_dst     = (const int*)d_in[9];
    const int* p_src  = (const int*)d_in[10];
    const int* p_dst  = (const int*)d_in[11];
    const int* p_qid  = (const int*)d_in[12];
    const int* users  = (const int*)d_in[13];
    const int* items  = (const int*)d_in[14];
    const int* negs   = (const int*)d_in[15];
    const int* query_words = (const int*)d_in[16];

    const int WORD = in_sizes[0] / 64;   // 50000
    const int Qn   = in_sizes[1] / 64;   // 50000
    const int N    = in_sizes[2] / 64;   // 100000
    const int R    = in_sizes[8] / 8;    // 100000
    const int E    = in_sizes[10];       // 2000000
    const int B    = in_sizes[13];       // 1024

    // layout: agg (f32 [N,128]) ALIASES the Pq/Pk/Vt/hrev block (dead by the
    // time gather_conv writes agg): 6.4+6.4+25.6+12.8 = 51.2 MB = agg size.
    ushort* e0b  = (ushort*)d_ws;                       // [N,128] bf16
    ushort* qe0b = e0b + (size_t)N * 128;               // [Qn,128] bf16
    ushort* Pq   = qe0b + (size_t)Qn * 128;             // [WORD,64] bf16
    ushort* Pk   = Pq + (size_t)WORD * 64;              // [WORD,64] bf16
    ushort* Vt   = Pk + (size_t)WORD * 64;              // [WORD,4,64] bf16
    ushort* hrev = Vt + (size_t)WORD * 256;             // [R,64] bf16
    float*  agg  = (float*)Pq;                          // aliases ^ (post-mega)
    float*  qb   = (float*)(hrev + (size_t)R * 64);     // [B,64] f32
    float*  inv  = qb + (size_t)B * 64;                 // [N]
    int* degc     = (int*)(inv + N);                    // [N]
    int* degp     = degc + N;                           // [N]
    int* offs     = degp + N;                           // [N+2]
    int* cursor   = offs + N + 2;                       // [N]
    int* offs_r   = cursor + N;                         // [N+2]
    int* cursor_r = offs_r + N + 2;                     // [N]
    int* csum     = cursor_r + N;                       // [256]
    int* csum2    = csum + 256;                         // [256]
    int* rmsg     = csum2 + 256;                        // [R]
    int2* msg     = (int2*)(rmsg + R);                  // [2E] 8B

    const int nchunk = (N + 1023) / 1024;               // 98

    hipMemsetAsync(degc, 0, 2 * (size_t)N * sizeof(int), stream);

    // PRE: count + proj(+Vt) + cvt fused
    {
        int nc_blk  = (E + 255) / 256;
        int npj_blk = (WORD + 3) / 4;
        int ncq_blk = (Qn * 16 + 255) / 256;
        int nce_blk = (N * 16 + 255) / 256;
        int mh_fam  = npj_blk + ncq_blk + nce_blk;
        int T = max(4 * nc_blk, (mh_fam * 4 + 2) / 3);
        T = ((T + 31) / 32) * 32;
        pre_kernel<<<T, 256, 0, stream>>>(W_word, Wq, Wk, Wv, Wo, Pq, Pk, Vt,
                                          W_query, W_entity, qe0b, e0b,
                                          p_src, p_dst, profile_dst, degc, degp,
                                          WORD, Qn, N, E, R,
                                          nc_blk, npj_blk, ncq_blk, nce_blk);
    }

    // fused scans
    scan_sum2<<<2 * nchunk, 256, 0, stream>>>(degc, degp, csum, csum2, N, nchunk);
    scan_blocks2<<<1, 256, 0, stream>>>(csum, csum2, nchunk);
    scan_chunk2<<<2 * nchunk, 256, 0, stream>>>(degc, degp, csum, csum2,
                                                offs, cursor, offs_r, cursor_r,
                                                inv, N, nchunk);

    // MEGA: MFMA-mhsa x3 + scatter_msgs + scatter_rev overlapped
    {
        int nr_blk = (R + 7) / 8;        // 4 waves/block, 2 seqs/wave
        int nq_blk = (Qn + 7) / 8;
        int nb_blk = (B + 7) / 8;
        int ns_blk = (E + 255) / 256;
        int nv_blk = (R + 255) / 256;
        int sc_fam = ns_blk + nv_blk;
        int mg_fam = nr_blk + nq_blk + nb_blk;
        int T = max(4 * sc_fam, (mg_fam * 4 + 2) / 3);
        T = ((T + 31) / 32) * 32;
        mega_kernel<<<T, 256, 0, stream>>>(Pq, Pk, Vt,
                                           query_word_ids, review_word_ids, query_words,
                                           qe0b, hrev, qb,
                                           p_src, p_dst, p_qid, profile_dst,
                                           cursor, msg, cursor_r, rmsg,
                                           Qn, R, B, E,
                                           nr_blk, nq_blk, nb_blk, ns_blk, nv_blk);
    }

    // ent_h -> e0b high half
    entity_gather<<<(N * 16 + 255) / 256, 256, 0, stream>>>(hrev, offs_r, rmsg, e0b, N);

    // conv gather (agg aliases dead Pq/Pk/Vt/hrev)
    gather_conv<<<(N * 16 + 255) / 256, 256, 0, stream>>>(e0b, qe0b, inv, offs, msg, agg, N);

    // outputs
    out_kernel<<<(B * 128 + 255) / 256, 256, 0, stream>>>(e0b, agg, inv, qb, users, items, negs, (float*)d_out, B);
}